// Round 1
// baseline (373.640 us; speedup 1.0000x reference)
//
#include <hip/hip_runtime.h>
#include <stdint.h>

// SetAbstraction forward, MI355X. B=2, N=4096, CIN=64, COUT=128, K=24.
// Pipeline: prep -> f1 -> ballquery1 -> dp -> FPS perm -> disp-MLP -> ballquery2 -> fused final.
// All reference reshapes are raw flat reinterpretations; replicated via flat index math.

#define BB 2
#define NN 4096
#define CI 64
#define CO 128
#define KK 24
#define GQ (BB*NN)        // 8192
#define NKK (NN*KK)       // 98304

__device__ __forceinline__ float relu_(float x){ return fmaxf(x, 0.0f); }

// ---------- kernel 0: copy pc -> out, extract p, transpose ww ----------
__global__ void k_prep(const float* __restrict__ pc, const float* __restrict__ ww,
                       float* __restrict__ outPc, float* __restrict__ p, float* __restrict__ wwT)
{
    int t = blockIdx.x*blockDim.x + threadIdx.x;
    int stride = gridDim.x*blockDim.x;
    for (int i = t; i < BB*NN*6; i += stride) {
        float v = pc[i];
        outPc[i] = v;
        int d = i % 6;
        if (d < 3) p[(i/6)*3 + d] = v;
    }
    for (int i = t; i < CO*CO; i += stride) {
        int o = i / CO, c = i % CO;
        wwT[c*CO + o] = ww[i];
    }
}

// ---------- kernel 1: f1 = relu(bn(w1 @ f)) ; (B,CO,N) ----------
__global__ void k_f1(const float* __restrict__ f, const float* __restrict__ w1,
                     const float* __restrict__ g1, const float* __restrict__ b1,
                     float* __restrict__ f1)
{
    int bid = blockIdx.x;                 // BB*CO*16 = 4096 blocks
    int chunk = bid & 15;
    int o = (bid >> 4) & 127;
    int b = bid >> 11;
    int n = chunk*256 + threadIdx.x;
    const float* frow = f + (size_t)b*CI*NN + n;
    float acc = 0.f;
    #pragma unroll 8
    for (int c = 0; c < CI; ++c)
        acc += w1[o*CI + c] * frow[(size_t)c*NN];
    float sc = g1[o] / sqrtf(1.00001f);
    f1[((size_t)b*CO + o)*NN + n] = relu_(acc*sc + b1[o]);
}

// ---------- kernel 2: ball query 1 -> idx (B,N,K): first K indices with d2<r2, pad with first ----------
__global__ void k_bq1(const float* __restrict__ p, int* __restrict__ idx)
{
    int wave = threadIdx.x >> 6;
    int lane = threadIdx.x & 63;
    int q = blockIdx.x*4 + wave;          // 0..8191
    int b = q >> 12;
    int n = q & 4095;
    const float* pb = p + (size_t)b*NN*3;
    float qx = pb[n*3+0], qy = pb[n*3+1], qz = pb[n*3+2];
    float sq = qx*qx + qy*qy + qz*qz;
    const float rsq = (float)(0.15*0.15);
    int cnt = 0, first = 0;
    int* orow = idx + (size_t)q*KK;
    for (int chunk = 0; chunk < 64; ++chunk) {
        int s = chunk*64 + lane;
        float sx = pb[s*3+0], sy = pb[s*3+1], sz = pb[s*3+2];
        float ss  = sx*sx + sy*sy + sz*sz;
        float dot = qx*sx + qy*sy + qz*sz;
        float d2 = (sq + ss) - 2.0f*dot;
        unsigned long long m = __ballot(d2 < rsq);
        while (m && cnt < KK) {
            int pos = __ffsll((unsigned long long)m) - 1;
            int sidx = chunk*64 + pos;
            if (cnt == 0) first = sidx;
            if (lane == 0) orow[cnt] = sidx;
            ++cnt;
            m &= m - 1;
        }
        if (cnt >= KK) break;
    }
    if (lane == 0)
        for (int j = cnt; j < KK; ++j) orow[j] = first;
}

// ---------- kernel 3: dp[b,d,n,k] = p[b,idx,d] - p[b,n,d] ----------
__global__ void k_mkdp(const float* __restrict__ p, const int* __restrict__ idx,
                       float* __restrict__ dp)
{
    int t = blockIdx.x*blockDim.x + threadIdx.x;   // 196608 exact
    int k = t % KK;
    int n = (t / KK) % NN;
    int b = t / (NN*KK);
    int j = idx[t];
    const float* pb = p + (size_t)b*NN*3;
    #pragma unroll
    for (int d = 0; d < 3; ++d)
        dp[(((size_t)b*3 + d)*NN + n)*KK + k] = pb[j*3+d] - pb[n*3+d];
}

// ---------- kernel 4: FPS permutation on each 24x3 row of dp.reshape(8192,24,3); writes permuted ----------
__global__ __launch_bounds__(64) void k_fps(const float* __restrict__ dp, float* __restrict__ ndp)
{
    __shared__ float P[3][KK][64];       // transposed: bank = tid%32, conflict-free
    int t = threadIdx.x;
    int row = blockIdx.x*64 + t;         // < 8192
    const float* src = dp + (size_t)row*72;
    float px[KK], py[KK], pz[KK];
    #pragma unroll
    for (int k = 0; k < KK; ++k) {
        float x = src[k*3+0], y = src[k*3+1], z = src[k*3+2];
        px[k]=x; py[k]=y; pz[k]=z;
        P[0][k][t]=x; P[1][k][t]=y; P[2][k][t]=z;
    }
    float* dst = ndp + (size_t)row*72;
    // perm[0] = 0
    dst[0] = px[0]; dst[1] = py[0]; dst[2] = pz[0];
    float dists[KK];
    #pragma unroll
    for (int k=0;k<KK;++k) dists[k]=1e10f;
    int last = 0;
    for (int j = 1; j < KK; ++j) {
        float lx = P[0][last][t], ly = P[1][last][t], lz = P[2][last][t];
        float best = -3.4e38f; int bk = 0;
        #pragma unroll
        for (int k = 0; k < KK; ++k) {
            float dx = px[k]-lx, dy = py[k]-ly, dz = pz[k]-lz;
            float d = dx*dx + dy*dy + dz*dz;
            float nd = fminf(dists[k], d);
            dists[k] = nd;
            if (nd > best) { best = nd; bk = k; }   // strict >: first-occurrence argmax
        }
        dst[j*3+0] = P[0][bk][t];
        dst[j*3+1] = P[1][bk][t];
        dst[j*3+2] = P[2][bk][t];
        last = bk;
    }
}

// ---------- kernel 5: displacement MLP (3->32->16->3) + residual add -> q2 ----------
__global__ void k_mlp(const float* __restrict__ ndp,
                      const float* __restrict__ wd1, const float* __restrict__ gd1, const float* __restrict__ bd1,
                      const float* __restrict__ wd2, const float* __restrict__ gd2, const float* __restrict__ bd2,
                      const float* __restrict__ wd3, const float* __restrict__ gd3, const float* __restrict__ bd3,
                      float* __restrict__ q2)
{
    __shared__ float W1[96], S1[32], B1s[32], W2[512], S2[16], B2s[16], W3[48], S3[3], B3s[3];
    int tid = threadIdx.x;
    const float inv = sqrtf(1.00001f);
    for (int i = tid; i < 96;  i += blockDim.x) W1[i]=wd1[i];
    for (int i = tid; i < 512; i += blockDim.x) W2[i]=wd2[i];
    for (int i = tid; i < 48;  i += blockDim.x) W3[i]=wd3[i];
    if (tid < 32) { S1[tid]=gd1[tid]/inv; B1s[tid]=bd1[tid]; }
    if (tid >= 32 && tid < 48) { int c=tid-32; S2[c]=gd2[c]/inv; B2s[c]=bd2[c]; }
    if (tid >= 48 && tid < 51) { int c=tid-48; S3[c]=gd3[c]/inv; B3s[c]=bd3[c]; }
    __syncthreads();
    int t = blockIdx.x*blockDim.x + tid;   // 196608 exact
    int k = t % KK, n = (t/KK)%NN, b = t/(NN*KK);
    size_t base = (((size_t)b*3)*NN + n)*KK + k;
    float x0 = ndp[base], x1 = ndp[base + NKK], x2 = ndp[base + 2*(size_t)NKK];
    float h1[32];
    #pragma unroll
    for (int o = 0; o < 32; ++o)
        h1[o] = relu_((W1[o*3+0]*x0 + W1[o*3+1]*x1 + W1[o*3+2]*x2)*S1[o] + B1s[o]);
    float h2[16];
    #pragma unroll
    for (int o = 0; o < 16; ++o) {
        float a = 0.f;
        #pragma unroll
        for (int c = 0; c < 32; ++c) a += W2[o*32+c]*h1[c];
        h2[o] = relu_(a*S2[o] + B2s[o]);
    }
    float xv[3] = {x0, x1, x2};
    #pragma unroll
    for (int d = 0; d < 3; ++d) {
        float a = 0.f;
        #pragma unroll
        for (int c = 0; c < 16; ++c) a += W3[d*16+c]*h2[c];
        q2[base + (size_t)d*NKK] = xv[d] + (a*S3[d] + B3s[d]);
    }
}

// ---------- kernel 6: ball query 2 (k=1) + dp2 = s2[j2] - q2 ----------
__global__ void k_bq2(const float* __restrict__ dpf, const float* __restrict__ q2f,
                      int* __restrict__ idx2, float* __restrict__ dp2)
{
    int t = blockIdx.x*blockDim.x + threadIdx.x;   // 196608 exact
    int g = t / KK, kq = t % KK;
    const float* srow = dpf + (size_t)g*72;
    const float* qp   = q2f + (size_t)g*72 + kq*3;
    float qx=qp[0], qy=qp[1], qz=qp[2];
    float sq = qx*qx + qy*qy + qz*qz;
    const float rsq = (float)(0.15*0.15);
    int j2 = 0;
    for (int s = 0; s < KK; ++s) {
        float sx=srow[s*3+0], sy=srow[s*3+1], sz=srow[s*3+2];
        float ss  = sx*sx + sy*sy + sz*sz;
        float dot = qx*sx + qy*sy + qz*sz;
        float d2 = (sq + ss) - 2.0f*dot;
        if (d2 < rsq) { j2 = s; break; }   // smallest index wins; none -> 0
    }
    idx2[t] = j2;
    float* drow = dp2 + (size_t)g*72;
    drow[0*KK + kq] = srow[j2*3+0] - qx;
    drow[1*KK + kq] = srow[j2*3+1] - qy;
    drow[2*KK + kq] = srow[j2*3+2] - qz;
}

// ---------- kernel 7: fused  fj2 gather + ww conv + softmax + pe + fout ----------
// fj2[b,c,n,k] = f1[b, c, idx[b, n, idx2[g,k]]],  g = (b*128+c)*32 + n/128
__global__ __launch_bounds__(128) void k_final(
    const float* __restrict__ f1, const int* __restrict__ idx, const int* __restrict__ idx2,
    const float* __restrict__ dp2, const float* __restrict__ wwT,
    const float* __restrict__ gw, const float* __restrict__ bw,
    const float* __restrict__ wc2, const float* __restrict__ gc2, const float* __restrict__ bc2,
    float* __restrict__ fout, float* __restrict__ pe)
{
    __shared__ float F[CO][28];   // row stride 28 floats (112B, 16B aligned)
    __shared__ float D[3][KK];
    __shared__ int   IR[KK];
    int tid = threadIdx.x;
    int bid = blockIdx.x;
    int b = bid >> 12, n = bid & 4095;
    if (tid < KK) IR[tid] = idx[((size_t)b*NN + n)*KK + tid];
    if (tid >= 32 && tid < 32+72) {
        int u = tid-32; int cd = u/KK, k = u%KK;
        D[cd][k] = dp2[(((size_t)b*3+cd)*NN + n)*KK + k];
    }
    __syncthreads();
    {   // gather F: this thread = channel c
        int c = tid;
        int g = (b*CO + c)*32 + (n >> 7);
        const int4* i4 = (const int4*)(idx2 + (size_t)g*KK);
        const float* frow = f1 + ((size_t)b*CO + c)*NN;
        #pragma unroll
        for (int q4 = 0; q4 < 6; ++q4) {
            int4 v = i4[q4];
            F[c][q4*4+0] = frow[IR[v.x]];
            F[c][q4*4+1] = frow[IR[v.y]];
            F[c][q4*4+2] = frow[IR[v.z]];
            F[c][q4*4+3] = frow[IR[v.w]];
        }
    }
    __syncthreads();
    const float inv = sqrtf(1.00001f);
    int o = tid;
    // pe = relu(bn(wc2 @ dp2))
    float w0 = wc2[o*3+0], w1 = wc2[o*3+1], w2 = wc2[o*3+2];
    float sc = gc2[o]/inv, bc = bc2[o];
    float pev[KK];
    #pragma unroll
    for (int k = 0; k < KK; ++k)
        pev[k] = relu_((w0*D[0][k] + w1*D[1][k] + w2*D[2][k])*sc + bc);
    // mod = softmax(bn(ww @ fj2)) over K
    float acc[KK];
    #pragma unroll
    for (int k=0;k<KK;++k) acc[k]=0.f;
    for (int c = 0; c < CO; ++c) {
        float wv = wwT[c*CO + o];
        const float4* Fr = (const float4*)(&F[c][0]);
        #pragma unroll
        for (int k4 = 0; k4 < 6; ++k4) {
            float4 fv = Fr[k4];
            acc[k4*4+0] += wv*fv.x;
            acc[k4*4+1] += wv*fv.y;
            acc[k4*4+2] += wv*fv.z;
            acc[k4*4+3] += wv*fv.w;
        }
    }
    float sw = gw[o]/inv, bwv = bw[o];
    float mx = -3.4e38f;
    #pragma unroll
    for (int k=0;k<KK;++k){ acc[k] = acc[k]*sw + bwv; mx = fmaxf(mx, acc[k]); }
    float ssum = 0.f;
    float e[KK];
    #pragma unroll
    for (int k=0;k<KK;++k){ e[k] = expf(acc[k]-mx); ssum += e[k]; }
    float fo = -3.4e38f;
    #pragma unroll
    for (int k=0;k<KK;++k){
        float mod = e[k]/ssum;
        float v = (pev[k] + F[o][k])*mod;
        fo = fmaxf(fo, v);
    }
    fout[((size_t)b*CO + o)*NN + n] = fo;
    float* perow = pe + (((size_t)b*CO + o)*NN + n)*(size_t)KK;
    #pragma unroll
    for (int k4 = 0; k4 < 6; ++k4) {
        float4 v;
        v.x=pev[k4*4+0]; v.y=pev[k4*4+1]; v.z=pev[k4*4+2]; v.w=pev[k4*4+3];
        ((float4*)perow)[k4] = v;
    }
}

extern "C" void kernel_launch(void* const* d_in, const int* in_sizes, int n_in,
                              void* d_out, int out_size, void* d_ws, size_t ws_size,
                              hipStream_t stream)
{
    const float* pc  = (const float*)d_in[0];
    const float* f   = (const float*)d_in[1];
    // d_in[2] = pe_in (unused, zeros)
    const float* w1  = (const float*)d_in[3];
    const float* g1  = (const float*)d_in[4];
    const float* b1  = (const float*)d_in[5];
    const float* wd1 = (const float*)d_in[6];
    const float* gd1 = (const float*)d_in[7];
    const float* bd1 = (const float*)d_in[8];
    const float* wd2 = (const float*)d_in[9];
    const float* gd2 = (const float*)d_in[10];
    const float* bd2 = (const float*)d_in[11];
    const float* wd3 = (const float*)d_in[12];
    const float* gd3 = (const float*)d_in[13];
    const float* bd3 = (const float*)d_in[14];
    const float* ww  = (const float*)d_in[15];
    const float* gw  = (const float*)d_in[16];
    const float* bw  = (const float*)d_in[17];
    const float* wc2 = (const float*)d_in[18];
    const float* gc2 = (const float*)d_in[19];
    const float* bc2 = (const float*)d_in[20];

    float* out     = (float*)d_out;
    float* outPc   = out;                               // 49152
    float* outFout = out + 49152;                       // 1048576
    float* outPe   = out + 49152 + 1048576;             // 25165824

    char* ws = (char*)d_ws;
    size_t off = 0;
    auto alloc = [&](size_t bytes)->void* {
        void* q = ws + off; off += (bytes + 255) & ~(size_t)255; return q;
    };
    float* p    = (float*)alloc((size_t)BB*NN*3*4);
    float* f1   = (float*)alloc((size_t)BB*CO*NN*4);
    int*   idx  = (int*)  alloc((size_t)BB*NN*KK*4);
    float* dpf  = (float*)alloc((size_t)BB*3*NN*KK*4);
    float* ndp  = (float*)alloc((size_t)BB*3*NN*KK*4);
    float* q2f  = (float*)alloc((size_t)BB*3*NN*KK*4);
    int*   idx2 = (int*)  alloc((size_t)GQ*KK*4);
    float* dp2  = (float*)alloc((size_t)GQ*72*4);
    float* wwT  = (float*)alloc((size_t)CO*CO*4);

    k_prep <<<dim3(128), dim3(256), 0, stream>>>(pc, ww, outPc, p, wwT);
    k_f1   <<<dim3(BB*CO*(NN/256)), dim3(256), 0, stream>>>(f, w1, g1, b1, f1);
    k_bq1  <<<dim3(GQ/4), dim3(256), 0, stream>>>(p, idx);
    k_mkdp <<<dim3((BB*NN*KK)/256), dim3(256), 0, stream>>>(p, idx, dpf);
    k_fps  <<<dim3(GQ/64), dim3(64), 0, stream>>>(dpf, ndp);
    k_mlp  <<<dim3((BB*NN*KK)/256), dim3(256), 0, stream>>>(ndp, wd1,gd1,bd1, wd2,gd2,bd2, wd3,gd3,bd3, q2f);
    k_bq2  <<<dim3((GQ*KK)/256), dim3(256), 0, stream>>>(dpf, q2f, idx2, dp2);
    k_final<<<dim3(GQ), dim3(128), 0, stream>>>(f1, idx, idx2, dp2, wwT, gw, bw, wc2, gc2, bc2, outFout, outPe);
}

// Round 2
// 289.657 us; speedup vs baseline: 1.2899x; 1.2899x over previous
//
#include <hip/hip_runtime.h>
#include <stdint.h>

// SetAbstraction forward, MI355X. B=2, N=4096, CIN=64, COUT=128, K=24.
// R2: coalesced gather via transposed f1 (f1T[b][n][c]), split-c k_final with
// LDS union (gather buf <-> reduce buf), float4-packed ww.

#define BB 2
#define NN 4096
#define CI 64
#define CO 128
#define KK 24
#define GQ (BB*NN)        // 8192
#define NKK (NN*KK)       // 98304

__device__ __forceinline__ float relu_(float x){ return fmaxf(x, 0.0f); }

// ---------- kernel 0: copy pc -> out, extract p, pack ww as float4 per c-quad ----------
// ww4[(c>>2)*512 + o*4 + (c&3)] = ww[o*128+c]
__global__ void k_prep(const float* __restrict__ pc, const float* __restrict__ ww,
                       float* __restrict__ outPc, float* __restrict__ p, float* __restrict__ ww4)
{
    int t = blockIdx.x*blockDim.x + threadIdx.x;
    int stride = gridDim.x*blockDim.x;
    for (int i = t; i < BB*NN*6; i += stride) {
        float v = pc[i];
        outPc[i] = v;
        int d = i % 6;
        if (d < 3) p[(i/6)*3 + d] = v;
    }
    for (int i = t; i < CO*CO; i += stride) {
        int o = i >> 7, c = i & 127;
        ww4[(c>>2)*512 + o*4 + (c&3)] = ww[i];
    }
}

// ---------- kernel 1: f1T[b][n][o] = relu(bn(w1 @ f)) ----------
__global__ __launch_bounds__(256) void k_f1(const float* __restrict__ f, const float* __restrict__ w1,
                     const float* __restrict__ g1, const float* __restrict__ b1,
                     float* __restrict__ f1T)
{
    __shared__ float W[CI*CO];           // w1T[c][o]
    int tid = threadIdx.x;
    for (int i = tid; i < CI*CO; i += 256) {
        int o = i >> 6, c = i & 63;
        W[c*CO + o] = w1[i];
    }
    __syncthreads();
    int bid = blockIdx.x;                // BB*NN/2 = 4096 blocks
    int b = bid >> 11;
    int n = (bid & 2047)*2 + (tid >> 7);
    int o = tid & 127;
    const float* fb = f + (size_t)b*CI*NN + n;
    float acc = 0.f;
    #pragma unroll 8
    for (int c = 0; c < CI; ++c)
        acc += W[c*CO + o] * fb[(size_t)c*NN];
    float sc = g1[o] / sqrtf(1.00001f);
    f1T[((size_t)b*NN + n)*CO + o] = relu_(acc*sc + b1[o]);
}

// ---------- kernel 2: ball query 1 -> idx (B,N,K) ----------
__global__ void k_bq1(const float* __restrict__ p, int* __restrict__ idx)
{
    int wave = threadIdx.x >> 6;
    int lane = threadIdx.x & 63;
    int q = blockIdx.x*4 + wave;          // 0..8191
    int b = q >> 12;
    int n = q & 4095;
    const float* pb = p + (size_t)b*NN*3;
    float qx = pb[n*3+0], qy = pb[n*3+1], qz = pb[n*3+2];
    float sq = qx*qx + qy*qy + qz*qz;
    const float rsq = (float)(0.15*0.15);
    int cnt = 0, first = 0;
    int* orow = idx + (size_t)q*KK;
    for (int chunk = 0; chunk < 64; ++chunk) {
        int s = chunk*64 + lane;
        float sx = pb[s*3+0], sy = pb[s*3+1], sz = pb[s*3+2];
        float ss  = sx*sx + sy*sy + sz*sz;
        float dot = qx*sx + qy*sy + qz*sz;
        float d2 = (sq + ss) - 2.0f*dot;
        unsigned long long m = __ballot(d2 < rsq);
        while (m && cnt < KK) {
            int pos = __ffsll((unsigned long long)m) - 1;
            int sidx = chunk*64 + pos;
            if (cnt == 0) first = sidx;
            if (lane == 0) orow[cnt] = sidx;
            ++cnt;
            m &= m - 1;
        }
        if (cnt >= KK) break;
    }
    if (lane == 0)
        for (int j = cnt; j < KK; ++j) orow[j] = first;
}

// ---------- kernel 3: dp[b,d,n,k] = p[b,idx,d] - p[b,n,d] ----------
__global__ void k_mkdp(const float* __restrict__ p, const int* __restrict__ idx,
                       float* __restrict__ dp)
{
    int t = blockIdx.x*blockDim.x + threadIdx.x;   // 196608 exact
    int k = t % KK;
    int n = (t / KK) % NN;
    int b = t / (NN*KK);
    int j = idx[t];
    const float* pb = p + (size_t)b*NN*3;
    #pragma unroll
    for (int d = 0; d < 3; ++d)
        dp[(((size_t)b*3 + d)*NN + n)*KK + k] = pb[j*3+d] - pb[n*3+d];
}

// ---------- kernel 4: FPS permutation on each 24x3 row ----------
__global__ __launch_bounds__(64) void k_fps(const float* __restrict__ dp, float* __restrict__ ndp)
{
    __shared__ float P[3][KK][64];
    int t = threadIdx.x;
    int row = blockIdx.x*64 + t;         // < 8192
    const float* src = dp + (size_t)row*72;
    float px[KK], py[KK], pz[KK];
    #pragma unroll
    for (int k = 0; k < KK; ++k) {
        float x = src[k*3+0], y = src[k*3+1], z = src[k*3+2];
        px[k]=x; py[k]=y; pz[k]=z;
        P[0][k][t]=x; P[1][k][t]=y; P[2][k][t]=z;
    }
    float* dst = ndp + (size_t)row*72;
    dst[0] = px[0]; dst[1] = py[0]; dst[2] = pz[0];
    float dists[KK];
    #pragma unroll
    for (int k=0;k<KK;++k) dists[k]=1e10f;
    int last = 0;
    for (int j = 1; j < KK; ++j) {
        float lx = P[0][last][t], ly = P[1][last][t], lz = P[2][last][t];
        float best = -3.4e38f; int bk = 0;
        #pragma unroll
        for (int k = 0; k < KK; ++k) {
            float dx = px[k]-lx, dy = py[k]-ly, dz = pz[k]-lz;
            float d = dx*dx + dy*dy + dz*dz;
            float nd = fminf(dists[k], d);
            dists[k] = nd;
            if (nd > best) { best = nd; bk = k; }   // strict >: first-occurrence argmax
        }
        dst[j*3+0] = P[0][bk][t];
        dst[j*3+1] = P[1][bk][t];
        dst[j*3+2] = P[2][bk][t];
        last = bk;
    }
}

// ---------- kernel 5: displacement MLP (3->32->16->3) + residual -> q2 ----------
__global__ void k_mlp(const float* __restrict__ ndp,
                      const float* __restrict__ wd1, const float* __restrict__ gd1, const float* __restrict__ bd1,
                      const float* __restrict__ wd2, const float* __restrict__ gd2, const float* __restrict__ bd2,
                      const float* __restrict__ wd3, const float* __restrict__ gd3, const float* __restrict__ bd3,
                      float* __restrict__ q2)
{
    __shared__ float W1[96], S1[32], B1s[32], W2[512], S2[16], B2s[16], W3[48], S3[3], B3s[3];
    int tid = threadIdx.x;
    const float inv = sqrtf(1.00001f);
    for (int i = tid; i < 96;  i += blockDim.x) W1[i]=wd1[i];
    for (int i = tid; i < 512; i += blockDim.x) W2[i]=wd2[i];
    for (int i = tid; i < 48;  i += blockDim.x) W3[i]=wd3[i];
    if (tid < 32) { S1[tid]=gd1[tid]/inv; B1s[tid]=bd1[tid]; }
    if (tid >= 32 && tid < 48) { int c=tid-32; S2[c]=gd2[c]/inv; B2s[c]=bd2[c]; }
    if (tid >= 48 && tid < 51) { int c=tid-48; S3[c]=gd3[c]/inv; B3s[c]=bd3[c]; }
    __syncthreads();
    int t = blockIdx.x*blockDim.x + tid;   // 196608 exact
    int k = t % KK, n = (t/KK)%NN, b = t/(NN*KK);
    size_t base = (((size_t)b*3)*NN + n)*KK + k;
    float x0 = ndp[base], x1 = ndp[base + NKK], x2 = ndp[base + 2*(size_t)NKK];
    float h1[32];
    #pragma unroll
    for (int o = 0; o < 32; ++o)
        h1[o] = relu_((W1[o*3+0]*x0 + W1[o*3+1]*x1 + W1[o*3+2]*x2)*S1[o] + B1s[o]);
    float h2[16];
    #pragma unroll
    for (int o = 0; o < 16; ++o) {
        float a = 0.f;
        #pragma unroll
        for (int c = 0; c < 32; ++c) a += W2[o*32+c]*h1[c];
        h2[o] = relu_(a*S2[o] + B2s[o]);
    }
    float xv[3] = {x0, x1, x2};
    #pragma unroll
    for (int d = 0; d < 3; ++d) {
        float a = 0.f;
        #pragma unroll
        for (int c = 0; c < 16; ++c) a += W3[d*16+c]*h2[c];
        q2[base + (size_t)d*NKK] = xv[d] + (a*S3[d] + B3s[d]);
    }
}

// ---------- kernel 6: ball query 2 (k=1) + dp2 = s2[j2] - q2 ----------
__global__ void k_bq2(const float* __restrict__ dpf, const float* __restrict__ q2f,
                      int* __restrict__ idx2, float* __restrict__ dp2)
{
    int t = blockIdx.x*blockDim.x + threadIdx.x;   // 196608 exact
    int g = t / KK, kq = t % KK;
    const float* srow = dpf + (size_t)g*72;
    const float* qp   = q2f + (size_t)g*72 + kq*3;
    float qx=qp[0], qy=qp[1], qz=qp[2];
    float sq = qx*qx + qy*qy + qz*qz;
    const float rsq = (float)(0.15*0.15);
    int j2 = 0;
    for (int s = 0; s < KK; ++s) {
        float sx=srow[s*3+0], sy=srow[s*3+1], sz=srow[s*3+2];
        float ss  = sx*sx + sy*sy + sz*sz;
        float dot = qx*sx + qy*sy + qz*sz;
        float d2 = (sq + ss) - 2.0f*dot;
        if (d2 < rsq) { j2 = s; break; }
    }
    idx2[t] = j2;
    float* drow = dp2 + (size_t)g*72;
    drow[0*KK + kq] = srow[j2*3+0] - qx;
    drow[1*KK + kq] = srow[j2*3+1] - qy;
    drow[2*KK + kq] = srow[j2*3+2] - qz;
}

// ---------- kernel 7: fused gather + ww conv + softmax + pe + fout ----------
// 256 threads: h = tid>>7 (c-half), o = tid&127.
// fj2[b,c,n,k] = f1T[b, IR[idx2[g,k]], c],  g = (b*128+c)*32 + n/128
__global__ __launch_bounds__(256) void k_final(
    const float* __restrict__ f1T, const int* __restrict__ idx, const int* __restrict__ idx2,
    const float* __restrict__ dp2, const float* __restrict__ ww4,
    const float* __restrict__ gw, const float* __restrict__ bw,
    const float* __restrict__ wc2, const float* __restrict__ gc2, const float* __restrict__ bc2,
    float* __restrict__ fout, float* __restrict__ pe)
{
    // LDS union: R0 = gather buffer Fb[c][kk] (stride 25) in phases 1-2,
    //            then reduce buffer red[o][k] (stride 28) in phase 4.
    __shared__ float R0[CO*28];
    __shared__ float Fs[CO*28];      // permuted F[c][k], stride 28
    __shared__ float Ds[3][KK];
    __shared__ int   IRs[KK];
    int tid = threadIdx.x;
    int bid = blockIdx.x;
    int b = bid >> 12, n = bid & 4095;

    // phase 0: indices + dp2 tile
    if (tid < KK) IRs[tid] = idx[((size_t)b*NN + n)*KK + tid];
    if (tid >= 32 && tid < 32+72) {
        int u = tid-32; int cd = u/KK, k = u%KK;
        Ds[cd][k] = dp2[(((size_t)b*3+cd)*NN + n)*KK + k];
    }
    __syncthreads();

    // phase 1: coalesced base gather. lane = channel c; halves split kk.
    {
        int c = tid & 127;
        int kk0 = (tid >> 7) * 12;
        const float* base = f1T + (size_t)b*NN*CO + c;
        #pragma unroll
        for (int j = 0; j < 12; ++j) {
            int kk = kk0 + j;
            R0[c*25 + kk] = base[(size_t)IRs[kk]*CO];
        }
    }
    __syncthreads();

    // phase 2: per-channel permute via idx2
    if (tid < CO) {
        int c = tid;
        int g = (b*CO + c)*32 + (n >> 7);
        const int4* i4 = (const int4*)(idx2 + (size_t)g*KK);
        int i2[KK];
        #pragma unroll
        for (int q4 = 0; q4 < 6; ++q4) {
            int4 v = i4[q4];
            i2[q4*4+0]=v.x; i2[q4*4+1]=v.y; i2[q4*4+2]=v.z; i2[q4*4+3]=v.w;
        }
        #pragma unroll
        for (int k = 0; k < KK; ++k)
            Fs[c*28 + k] = R0[c*25 + i2[k]];
    }
    __syncthreads();   // also protects R0 reuse as reduce buffer

    // phase 3: split-c conv. h covers c in [h*64, h*64+64)
    int o = tid & 127;
    int h = tid >> 7;
    float acc[KK];
    #pragma unroll
    for (int k=0;k<KK;++k) acc[k]=0.f;
    int cq0 = h*16;
    #pragma unroll 4
    for (int cq = 0; cq < 16; ++cq) {
        int cquad = cq0 + cq;
        float4 w4 = *(const float4*)&ww4[(size_t)cquad*512 + o*4];
        const float* Fr0 = &Fs[(cquad*4+0)*28];
        const float* Fr1 = &Fs[(cquad*4+1)*28];
        const float* Fr2 = &Fs[(cquad*4+2)*28];
        const float* Fr3 = &Fs[(cquad*4+3)*28];
        #pragma unroll
        for (int k4 = 0; k4 < 6; ++k4) {
            float4 f0 = ((const float4*)Fr0)[k4];
            float4 f1v = ((const float4*)Fr1)[k4];
            float4 f2 = ((const float4*)Fr2)[k4];
            float4 f3 = ((const float4*)Fr3)[k4];
            acc[k4*4+0] += w4.x*f0.x + w4.y*f1v.x + w4.z*f2.x + w4.w*f3.x;
            acc[k4*4+1] += w4.x*f0.y + w4.y*f1v.y + w4.z*f2.y + w4.w*f3.y;
            acc[k4*4+2] += w4.x*f0.z + w4.y*f1v.z + w4.z*f2.z + w4.w*f3.z;
            acc[k4*4+3] += w4.x*f0.w + w4.y*f1v.w + w4.z*f2.w + w4.w*f3.w;
        }
    }

    // phase 4: reduce halves via R0 (now red[o][k], stride 28)
    if (h == 1) {
        #pragma unroll
        for (int k4 = 0; k4 < 6; ++k4) {
            float4 v; v.x=acc[k4*4+0]; v.y=acc[k4*4+1]; v.z=acc[k4*4+2]; v.w=acc[k4*4+3];
            ((float4*)&R0[o*28])[k4] = v;
        }
    }
    __syncthreads();
    if (h == 1) return;

    #pragma unroll
    for (int k4 = 0; k4 < 6; ++k4) {
        float4 v = ((const float4*)&R0[o*28])[k4];
        acc[k4*4+0]+=v.x; acc[k4*4+1]+=v.y; acc[k4*4+2]+=v.z; acc[k4*4+3]+=v.w;
    }

    // epilogue: bn + softmax + pe + fout
    const float inv = sqrtf(1.00001f);
    float w0 = wc2[o*3+0], w1v = wc2[o*3+1], w2 = wc2[o*3+2];
    float sc = gc2[o]/inv, bc = bc2[o];
    float pev[KK];
    #pragma unroll
    for (int k = 0; k < KK; ++k)
        pev[k] = relu_((w0*Ds[0][k] + w1v*Ds[1][k] + w2*Ds[2][k])*sc + bc);
    float sw = gw[o]/inv, bwv = bw[o];
    float mx = -3.4e38f;
    #pragma unroll
    for (int k=0;k<KK;++k){ acc[k] = acc[k]*sw + bwv; mx = fmaxf(mx, acc[k]); }
    float ssum = 0.f;
    float e[KK];
    #pragma unroll
    for (int k=0;k<KK;++k){ e[k] = expf(acc[k]-mx); ssum += e[k]; }
    float fo = -3.4e38f;
    #pragma unroll
    for (int k=0;k<KK;++k){
        float mod = e[k]/ssum;
        float v = (pev[k] + Fs[o*28+k])*mod;
        fo = fmaxf(fo, v);
    }
    fout[((size_t)b*CO + o)*NN + n] = fo;
    float* perow = pe + (((size_t)b*CO + o)*NN + n)*(size_t)KK;
    #pragma unroll
    for (int k4 = 0; k4 < 6; ++k4) {
        float4 v;
        v.x=pev[k4*4+0]; v.y=pev[k4*4+1]; v.z=pev[k4*4+2]; v.w=pev[k4*4+3];
        ((float4*)perow)[k4] = v;
    }
}

extern "C" void kernel_launch(void* const* d_in, const int* in_sizes, int n_in,
                              void* d_out, int out_size, void* d_ws, size_t ws_size,
                              hipStream_t stream)
{
    const float* pc  = (const float*)d_in[0];
    const float* f   = (const float*)d_in[1];
    const float* w1  = (const float*)d_in[3];
    const float* g1  = (const float*)d_in[4];
    const float* b1  = (const float*)d_in[5];
    const float* wd1 = (const float*)d_in[6];
    const float* gd1 = (const float*)d_in[7];
    const float* bd1 = (const float*)d_in[8];
    const float* wd2 = (const float*)d_in[9];
    const float* gd2 = (const float*)d_in[10];
    const float* bd2 = (const float*)d_in[11];
    const float* wd3 = (const float*)d_in[12];
    const float* gd3 = (const float*)d_in[13];
    const float* bd3 = (const float*)d_in[14];
    const float* ww  = (const float*)d_in[15];
    const float* gw  = (const float*)d_in[16];
    const float* bw  = (const float*)d_in[17];
    const float* wc2 = (const float*)d_in[18];
    const float* gc2 = (const float*)d_in[19];
    const float* bc2 = (const float*)d_in[20];

    float* out     = (float*)d_out;
    float* outPc   = out;                               // 49152
    float* outFout = out + 49152;                       // 1048576
    float* outPe   = out + 49152 + 1048576;             // 25165824

    char* ws = (char*)d_ws;
    size_t off = 0;
    auto alloc = [&](size_t bytes)->void* {
        void* q = ws + off; off += (bytes + 255) & ~(size_t)255; return q;
    };
    float* p    = (float*)alloc((size_t)BB*NN*3*4);
    float* f1T  = (float*)alloc((size_t)BB*NN*CO*4);
    int*   idx  = (int*)  alloc((size_t)BB*NN*KK*4);
    float* dpf  = (float*)alloc((size_t)BB*3*NN*KK*4);
    float* ndp  = (float*)alloc((size_t)BB*3*NN*KK*4);
    float* q2f  = (float*)alloc((size_t)BB*3*NN*KK*4);
    int*   idx2 = (int*)  alloc((size_t)GQ*KK*4);
    float* dp2  = (float*)alloc((size_t)GQ*72*4);
    float* ww4  = (float*)alloc((size_t)CO*CO*4);

    k_prep <<<dim3(128), dim3(256), 0, stream>>>(pc, ww, outPc, p, ww4);
    k_f1   <<<dim3(BB*NN/2), dim3(256), 0, stream>>>(f, w1, g1, b1, f1T);
    k_bq1  <<<dim3(GQ/4), dim3(256), 0, stream>>>(p, idx);
    k_mkdp <<<dim3((BB*NN*KK)/256), dim3(256), 0, stream>>>(p, idx, dpf);
    k_fps  <<<dim3(GQ/64), dim3(64), 0, stream>>>(dpf, ndp);
    k_mlp  <<<dim3((BB*NN*KK)/256), dim3(256), 0, stream>>>(ndp, wd1,gd1,bd1, wd2,gd2,bd2, wd3,gd3,bd3, q2f);
    k_bq2  <<<dim3((GQ*KK)/256), dim3(256), 0, stream>>>(dpf, q2f, idx2, dp2);
    k_final<<<dim3(GQ), dim3(256), 0, stream>>>(f1T, idx, idx2, dp2, ww4, gw, bw, wc2, gc2, bc2, outFout, outPe);
}

// Round 3
// 265.611 us; speedup vs baseline: 1.4067x; 1.0905x over previous
//
#include <hip/hip_runtime.h>
#include <stdint.h>

// SetAbstraction forward, MI355X. B=2, N=4096, CIN=64, COUT=128, K=24.
// R3: k_final register-blocked (2o x 12k x 1n per thread, 2n per block),
// shfl-pair softmax (no reduce phase), __expf + single rcp, Fs[k][c] layout,
// idx2 shared across the block's two n's, prep merged into k_f1.

#define BB 2
#define NN 4096
#define CI 64
#define CO 128
#define KK 24
#define GQ (BB*NN)        // 8192
#define NKK (NN*KK)       // 98304

__device__ __forceinline__ float relu_(float x){ return fmaxf(x, 0.0f); }

// ---------- kernel 1: f1T[b][n][o] = relu(bn(w1 @ f))  + prep (pc copy, p extract, wwP pack) ----------
// wwP[(cq*64 + op)*8 + oh*4 + e] = ww[(2*op+oh)*128 + cq*4+e]
__global__ __launch_bounds__(256) void k_f1(const float* __restrict__ f, const float* __restrict__ w1,
                     const float* __restrict__ g1, const float* __restrict__ b1,
                     const float* __restrict__ pc, const float* __restrict__ ww,
                     float* __restrict__ f1T, float* __restrict__ outPc,
                     float* __restrict__ p, float* __restrict__ wwP)
{
    int tid = threadIdx.x;
    int bid = blockIdx.x;
    // prep work (independent of f1)
    {
        int t = bid*256 + tid;
        if (t < BB*NN*6) {
            float v = pc[t];
            outPc[t] = v;
            int d = t % 6;
            if (d < 3) p[(t/6)*3 + d] = v;
        }
        if (t < CO*CO) {
            int o = t >> 7, c = t & 127;
            int op = o >> 1, oh = o & 1, cq = c >> 2, e = c & 3;
            wwP[(cq*64 + op)*8 + oh*4 + e] = ww[t];
        }
    }
    __shared__ float W[CI*CO];           // w1T[c][o]
    for (int i = tid; i < CI*CO; i += 256) {
        int o = i >> 6, c = i & 63;
        W[c*CO + o] = w1[i];
    }
    __syncthreads();
    int b = bid >> 11;
    int n = (bid & 2047)*2 + (tid >> 7);
    int o = tid & 127;
    const float* fb = f + (size_t)b*CI*NN + n;
    float acc = 0.f;
    #pragma unroll 8
    for (int c = 0; c < CI; ++c)
        acc += W[c*CO + o] * fb[(size_t)c*NN];
    float sc = g1[o] / sqrtf(1.00001f);
    f1T[((size_t)b*NN + n)*CO + o] = relu_(acc*sc + b1[o]);
}

// ---------- kernel 2: ball query 1 -> idx (B,N,K) ----------
__global__ void k_bq1(const float* __restrict__ p, int* __restrict__ idx)
{
    int wave = threadIdx.x >> 6;
    int lane = threadIdx.x & 63;
    int q = blockIdx.x*4 + wave;          // 0..8191
    int b = q >> 12;
    int n = q & 4095;
    const float* pb = p + (size_t)b*NN*3;
    float qx = pb[n*3+0], qy = pb[n*3+1], qz = pb[n*3+2];
    float sq = qx*qx + qy*qy + qz*qz;
    const float rsq = (float)(0.15*0.15);
    int cnt = 0, first = 0;
    int* orow = idx + (size_t)q*KK;
    for (int chunk = 0; chunk < 64; ++chunk) {
        int s = chunk*64 + lane;
        float sx = pb[s*3+0], sy = pb[s*3+1], sz = pb[s*3+2];
        float ss  = sx*sx + sy*sy + sz*sz;
        float dot = qx*sx + qy*sy + qz*sz;
        float d2 = (sq + ss) - 2.0f*dot;
        unsigned long long m = __ballot(d2 < rsq);
        while (m && cnt < KK) {
            int pos = __ffsll((unsigned long long)m) - 1;
            int sidx = chunk*64 + pos;
            if (cnt == 0) first = sidx;
            if (lane == 0) orow[cnt] = sidx;
            ++cnt;
            m &= m - 1;
        }
        if (cnt >= KK) break;
    }
    if (lane == 0)
        for (int j = cnt; j < KK; ++j) orow[j] = first;
}

// ---------- kernel 3: dp[b,d,n,k] = p[b,idx,d] - p[b,n,d] ----------
__global__ void k_mkdp(const float* __restrict__ p, const int* __restrict__ idx,
                       float* __restrict__ dp)
{
    int t = blockIdx.x*blockDim.x + threadIdx.x;   // 196608 exact
    int k = t % KK;
    int n = (t / KK) % NN;
    int b = t / (NN*KK);
    int j = idx[t];
    const float* pb = p + (size_t)b*NN*3;
    #pragma unroll
    for (int d = 0; d < 3; ++d)
        dp[(((size_t)b*3 + d)*NN + n)*KK + k] = pb[j*3+d] - pb[n*3+d];
}

// ---------- kernel 4: FPS permutation on each 24x3 row ----------
__global__ __launch_bounds__(64) void k_fps(const float* __restrict__ dp, float* __restrict__ ndp)
{
    __shared__ float P[3][KK][64];
    int t = threadIdx.x;
    int row = blockIdx.x*64 + t;         // < 8192
    const float* src = dp + (size_t)row*72;
    float px[KK], py[KK], pz[KK];
    #pragma unroll
    for (int k = 0; k < KK; ++k) {
        float x = src[k*3+0], y = src[k*3+1], z = src[k*3+2];
        px[k]=x; py[k]=y; pz[k]=z;
        P[0][k][t]=x; P[1][k][t]=y; P[2][k][t]=z;
    }
    float* dst = ndp + (size_t)row*72;
    dst[0] = px[0]; dst[1] = py[0]; dst[2] = pz[0];
    float dists[KK];
    #pragma unroll
    for (int k=0;k<KK;++k) dists[k]=1e10f;
    int last = 0;
    for (int j = 1; j < KK; ++j) {
        float lx = P[0][last][t], ly = P[1][last][t], lz = P[2][last][t];
        float best = -3.4e38f; int bk = 0;
        #pragma unroll
        for (int k = 0; k < KK; ++k) {
            float dx = px[k]-lx, dy = py[k]-ly, dz = pz[k]-lz;
            float d = dx*dx + dy*dy + dz*dz;
            float nd = fminf(dists[k], d);
            dists[k] = nd;
            if (nd > best) { best = nd; bk = k; }   // strict >: first-occurrence argmax
        }
        dst[j*3+0] = P[0][bk][t];
        dst[j*3+1] = P[1][bk][t];
        dst[j*3+2] = P[2][bk][t];
        last = bk;
    }
}

// ---------- kernel 5: displacement MLP (3->32->16->3) + residual -> q2 ----------
__global__ void k_mlp(const float* __restrict__ ndp,
                      const float* __restrict__ wd1, const float* __restrict__ gd1, const float* __restrict__ bd1,
                      const float* __restrict__ wd2, const float* __restrict__ gd2, const float* __restrict__ bd2,
                      const float* __restrict__ wd3, const float* __restrict__ gd3, const float* __restrict__ bd3,
                      float* __restrict__ q2)
{
    __shared__ float W1[96], S1[32], B1s[32], W2[512], S2[16], B2s[16], W3[48], S3[3], B3s[3];
    int tid = threadIdx.x;
    const float inv = sqrtf(1.00001f);
    for (int i = tid; i < 96;  i += blockDim.x) W1[i]=wd1[i];
    for (int i = tid; i < 512; i += blockDim.x) W2[i]=wd2[i];
    for (int i = tid; i < 48;  i += blockDim.x) W3[i]=wd3[i];
    if (tid < 32) { S1[tid]=gd1[tid]/inv; B1s[tid]=bd1[tid]; }
    if (tid >= 32 && tid < 48) { int c=tid-32; S2[c]=gd2[c]/inv; B2s[c]=bd2[c]; }
    if (tid >= 48 && tid < 51) { int c=tid-48; S3[c]=gd3[c]/inv; B3s[c]=bd3[c]; }
    __syncthreads();
    int t = blockIdx.x*blockDim.x + tid;   // 196608 exact
    int k = t % KK, n = (t/KK)%NN, b = t/(NN*KK);
    size_t base = (((size_t)b*3)*NN + n)*KK + k;
    float x0 = ndp[base], x1 = ndp[base + NKK], x2 = ndp[base + 2*(size_t)NKK];
    float h1[32];
    #pragma unroll
    for (int o = 0; o < 32; ++o)
        h1[o] = relu_((W1[o*3+0]*x0 + W1[o*3+1]*x1 + W1[o*3+2]*x2)*S1[o] + B1s[o]);
    float h2[16];
    #pragma unroll
    for (int o = 0; o < 16; ++o) {
        float a = 0.f;
        #pragma unroll
        for (int c = 0; c < 32; ++c) a += W2[o*32+c]*h1[c];
        h2[o] = relu_(a*S2[o] + B2s[o]);
    }
    float xv[3] = {x0, x1, x2};
    #pragma unroll
    for (int d = 0; d < 3; ++d) {
        float a = 0.f;
        #pragma unroll
        for (int c = 0; c < 16; ++c) a += W3[d*16+c]*h2[c];
        q2[base + (size_t)d*NKK] = xv[d] + (a*S3[d] + B3s[d]);
    }
}

// ---------- kernel 6: ball query 2 (k=1) + dp2 = s2[j2] - q2 ----------
__global__ void k_bq2(const float* __restrict__ dpf, const float* __restrict__ q2f,
                      int* __restrict__ idx2, float* __restrict__ dp2)
{
    int t = blockIdx.x*blockDim.x + threadIdx.x;   // 196608 exact
    int g = t / KK, kq = t % KK;
    const float* srow = dpf + (size_t)g*72;
    const float* qp   = q2f + (size_t)g*72 + kq*3;
    float qx=qp[0], qy=qp[1], qz=qp[2];
    float sq = qx*qx + qy*qy + qz*qz;
    const float rsq = (float)(0.15*0.15);
    int j2 = 0;
    for (int s = 0; s < KK; ++s) {
        float sx=srow[s*3+0], sy=srow[s*3+1], sz=srow[s*3+2];
        float ss  = sx*sx + sy*sy + sz*sz;
        float dot = qx*sx + qy*sy + qz*sz;
        float d2 = (sq + ss) - 2.0f*dot;
        if (d2 < rsq) { j2 = s; break; }
    }
    idx2[t] = j2;
    float* drow = dp2 + (size_t)g*72;
    drow[0*KK + kq] = srow[j2*3+0] - qx;
    drow[1*KK + kq] = srow[j2*3+1] - qy;
    drow[2*KK + kq] = srow[j2*3+2] - qz;
}

// ---------- kernel 7: fused gather + ww conv + softmax + pe + fout ----------
// Block: 2 n's. Thread (nl = tid>>7, op = (tid&127)>>1, half = tid&1):
// owns o in {2op, 2op+1}, k in [half*12, half*12+12), for n = n0+nl.
// Softmax/fout combine across k-halves via shfl_xor(1).
// fj2[b,c,n,k] = f1T[b, IR[n][idx2[g(c,n0)][k]], c]
__global__ __launch_bounds__(256, 4) void k_final(
    const float* __restrict__ f1T, const int* __restrict__ idx, const int* __restrict__ idx2,
    const float* __restrict__ dp2, const float* __restrict__ wwP,
    const float* __restrict__ gw, const float* __restrict__ bw,
    const float* __restrict__ wc2, const float* __restrict__ gc2, const float* __restrict__ bc2,
    float* __restrict__ fout, float* __restrict__ pe)
{
    __shared__ float G[CO*25];          // gather staging [c][kk], stride 25
    __shared__ float Fs[2*KK*132];      // permuted [n][k][c], stride 132 (16B-aligned rows)
    __shared__ float Ds[2][3][KK];
    __shared__ int   IRs[2][KK];
    int tid = threadIdx.x;
    int bid = blockIdx.x;
    int b = bid >> 11;
    int n0 = (bid & 2047)*2;

    // phase 0: indices + dp2 tiles + per-thread idx2 regs
    if (tid < 48) {
        int nl = tid/24, kk = tid%24;
        IRs[nl][kk] = idx[((size_t)b*NN + (n0+nl))*KK + kk];
    }
    if (tid >= 64 && tid < 208) {
        int u = tid-64; int nl = u/72, r = u%72, d = r/24, k = r%24;
        Ds[nl][d][k] = dp2[(((size_t)b*3 + d)*NN + (n0+nl))*KK + k];
    }
    int c = tid & 127, kh = tid >> 7;
    int i2r[12];
    {
        int g = (b*CO + c)*32 + (n0 >> 7);          // same for both n's in block
        const int4* i4 = (const int4*)(idx2 + (size_t)g*KK) + kh*3;
        int4 a = i4[0], bq = i4[1], cq4 = i4[2];
        i2r[0]=a.x; i2r[1]=a.y; i2r[2]=a.z; i2r[3]=a.w;
        i2r[4]=bq.x; i2r[5]=bq.y; i2r[6]=bq.z; i2r[7]=bq.w;
        i2r[8]=cq4.x; i2r[9]=cq4.y; i2r[10]=cq4.z; i2r[11]=cq4.w;
    }
    __syncthreads();

    // gather + permute, per n (G reused)
    const float* basep = f1T + (size_t)b*NN*CO + c;
    #pragma unroll
    for (int nl = 0; nl < 2; ++nl) {
        #pragma unroll
        for (int j = 0; j < 12; ++j) {
            int kk = kh*12 + j;
            G[c*25 + kk] = basep[(size_t)IRs[nl][kk]*CO];
        }
        __syncthreads();
        #pragma unroll
        for (int j = 0; j < 12; ++j) {
            int k = kh*12 + j;
            Fs[(nl*KK + k)*132 + c] = G[c*25 + i2r[j]];
        }
        __syncthreads();
    }

    // conv: acc[oo][j] = sum_c ww[2op+oo][c] * Fs[nl][k0+j][c]
    int op = (tid & 127) >> 1, half = tid & 1, nl = tid >> 7;
    int k0 = half*12;
    float acc0[12], acc1[12];
    #pragma unroll
    for (int j=0;j<12;++j){ acc0[j]=0.f; acc1[j]=0.f; }
    const float* fsn = Fs + (nl*KK + k0)*132;
    #pragma unroll 4
    for (int cq = 0; cq < 32; ++cq) {
        float4 wa = *(const float4*)&wwP[(cq*64 + op)*8];
        float4 wb = *(const float4*)&wwP[(cq*64 + op)*8 + 4];
        #pragma unroll
        for (int j = 0; j < 12; ++j) {
            float4 f4 = *(const float4*)&fsn[j*132 + cq*4];
            acc0[j] += wa.x*f4.x + wa.y*f4.y + wa.z*f4.z + wa.w*f4.w;
            acc1[j] += wb.x*f4.x + wb.y*f4.y + wb.z*f4.z + wb.w*f4.w;
        }
    }

    // epilogue
    const float inv = sqrtf(1.00001f);
    int o0 = op*2;
    int n  = n0 + nl;
    float sw0 = gw[o0]/inv,   bw0 = bw[o0];
    float sw1 = gw[o0+1]/inv, bw1 = bw[o0+1];
    float pev0[12], pev1[12];
    {
        float wa0=wc2[o0*3], wa1=wc2[o0*3+1], wa2=wc2[o0*3+2];
        float wb0=wc2[o0*3+3], wb1=wc2[o0*3+4], wb2=wc2[o0*3+5];
        float sca = gc2[o0]/inv,   bca = bc2[o0];
        float scb = gc2[o0+1]/inv, bcb = bc2[o0+1];
        #pragma unroll
        for (int j = 0; j < 12; ++j) {
            float d0 = Ds[nl][0][k0+j], d1 = Ds[nl][1][k0+j], d2 = Ds[nl][2][k0+j];
            pev0[j] = relu_((wa0*d0 + wa1*d1 + wa2*d2)*sca + bca);
            pev1[j] = relu_((wb0*d0 + wb1*d1 + wb2*d2)*scb + bcb);
        }
    }
    float m0 = -3.4e38f, m1 = -3.4e38f;
    #pragma unroll
    for (int j=0;j<12;++j){
        acc0[j] = acc0[j]*sw0 + bw0; m0 = fmaxf(m0, acc0[j]);
        acc1[j] = acc1[j]*sw1 + bw1; m1 = fmaxf(m1, acc1[j]);
    }
    m0 = fmaxf(m0, __shfl_xor(m0, 1));
    m1 = fmaxf(m1, __shfl_xor(m1, 1));
    float s0 = 0.f, s1 = 0.f;
    #pragma unroll
    for (int j=0;j<12;++j){
        acc0[j] = __expf(acc0[j]-m0); s0 += acc0[j];
        acc1[j] = __expf(acc1[j]-m1); s1 += acc1[j];
    }
    s0 += __shfl_xor(s0, 1);
    s1 += __shfl_xor(s1, 1);
    float rs0 = 1.0f/s0, rs1 = 1.0f/s1;
    float fo0 = -3.4e38f, fo1 = -3.4e38f;
    #pragma unroll
    for (int j=0;j<12;++j){
        float fj0 = fsn[j*132 + o0];
        float fj1 = fsn[j*132 + o0+1];
        fo0 = fmaxf(fo0, (pev0[j] + fj0)*acc0[j]*rs0);
        fo1 = fmaxf(fo1, (pev1[j] + fj1)*acc1[j]*rs1);
    }
    fo0 = fmaxf(fo0, __shfl_xor(fo0, 1));
    fo1 = fmaxf(fo1, __shfl_xor(fo1, 1));
    fout[((size_t)b*CO + o0+half)*NN + n] = half ? fo1 : fo0;
    float* pr0 = pe + (((size_t)b*CO + o0)*NN + n)*KK + k0;
    float* pr1 = pe + (((size_t)b*CO + o0+1)*NN + n)*KK + k0;
    #pragma unroll
    for (int q4 = 0; q4 < 3; ++q4) {
        float4 v0, v1;
        v0.x=pev0[q4*4+0]; v0.y=pev0[q4*4+1]; v0.z=pev0[q4*4+2]; v0.w=pev0[q4*4+3];
        v1.x=pev1[q4*4+0]; v1.y=pev1[q4*4+1]; v1.z=pev1[q4*4+2]; v1.w=pev1[q4*4+3];
        ((float4*)pr0)[q4] = v0;
        ((float4*)pr1)[q4] = v1;
    }
}

extern "C" void kernel_launch(void* const* d_in, const int* in_sizes, int n_in,
                              void* d_out, int out_size, void* d_ws, size_t ws_size,
                              hipStream_t stream)
{
    const float* pc  = (const float*)d_in[0];
    const float* f   = (const float*)d_in[1];
    const float* w1  = (const float*)d_in[3];
    const float* g1  = (const float*)d_in[4];
    const float* b1  = (const float*)d_in[5];
    const float* wd1 = (const float*)d_in[6];
    const float* gd1 = (const float*)d_in[7];
    const float* bd1 = (const float*)d_in[8];
    const float* wd2 = (const float*)d_in[9];
    const float* gd2 = (const float*)d_in[10];
    const float* bd2 = (const float*)d_in[11];
    const float* wd3 = (const float*)d_in[12];
    const float* gd3 = (const float*)d_in[13];
    const float* bd3 = (const float*)d_in[14];
    const float* ww  = (const float*)d_in[15];
    const float* gw  = (const float*)d_in[16];
    const float* bw  = (const float*)d_in[17];
    const float* wc2 = (const float*)d_in[18];
    const float* gc2 = (const float*)d_in[19];
    const float* bc2 = (const float*)d_in[20];

    float* out     = (float*)d_out;
    float* outPc   = out;                               // 49152
    float* outFout = out + 49152;                       // 1048576
    float* outPe   = out + 49152 + 1048576;             // 25165824

    char* ws = (char*)d_ws;
    size_t off = 0;
    auto alloc = [&](size_t bytes)->void* {
        void* q = ws + off; off += (bytes + 255) & ~(size_t)255; return q;
    };
    float* p    = (float*)alloc((size_t)BB*NN*3*4);
    float* f1T  = (float*)alloc((size_t)BB*NN*CO*4);
    int*   idx  = (int*)  alloc((size_t)BB*NN*KK*4);
    float* dpf  = (float*)alloc((size_t)BB*3*NN*KK*4);
    float* ndp  = (float*)alloc((size_t)BB*3*NN*KK*4);
    float* q2f  = (float*)alloc((size_t)BB*3*NN*KK*4);
    int*   idx2 = (int*)  alloc((size_t)GQ*KK*4);
    float* dp2  = (float*)alloc((size_t)GQ*72*4);
    float* wwP  = (float*)alloc((size_t)CO*CO*4);

    k_f1   <<<dim3(BB*NN/2), dim3(256), 0, stream>>>(f, w1, g1, b1, pc, ww, f1T, outPc, p, wwP);
    k_bq1  <<<dim3(GQ/4), dim3(256), 0, stream>>>(p, idx);
    k_mkdp <<<dim3((BB*NN*KK)/256), dim3(256), 0, stream>>>(p, idx, dpf);
    k_fps  <<<dim3(GQ/64), dim3(64), 0, stream>>>(dpf, ndp);
    k_mlp  <<<dim3((BB*NN*KK)/256), dim3(256), 0, stream>>>(ndp, wd1,gd1,bd1, wd2,gd2,bd2, wd3,gd3,bd3, q2f);
    k_bq2  <<<dim3((GQ*KK)/256), dim3(256), 0, stream>>>(dpf, q2f, idx2, dp2);
    k_final<<<dim3(BB*NN/2), dim3(256), 0, stream>>>(f1T, idx, idx2, dp2, wwP, gw, bw, wc2, gc2, bc2, outFout, outPe);
}

// Round 4
// 178.127 us; speedup vs baseline: 2.0976x; 1.4911x over previous
//
#include <hip/hip_runtime.h>
#include <stdint.h>

// SetAbstraction forward, MI355X. B=2, N=4096, CIN=64, COUT=128, K=24.
// R4: k_final conv -> bf16 MFMA (16x16x32). Fbf[col][c] bf16 XOR-swizzled B-tile,
// ww prepacked in A-fragment lane order, M[col][o] f32 LDS (overlaid on gather buf),
// epilogue identical to R3 reading M. Everything else unchanged from R3 (passing).

#define BB 2
#define NN 4096
#define CI 64
#define CO 128
#define KK 24
#define GQ (BB*NN)        // 8192
#define NKK (NN*KK)       // 98304

typedef __attribute__((ext_vector_type(8))) short short8;
typedef __attribute__((ext_vector_type(4))) float f32x4;

__device__ __forceinline__ float relu_(float x){ return fmaxf(x, 0.0f); }
__device__ __forceinline__ unsigned short f2bf(float x){
    unsigned int u = __float_as_uint(x);
    return (unsigned short)((u + 0x7FFFu + ((u>>16)&1u)) >> 16);
}

// ---------- kernel 1: f1T[b][n][o] = relu(bn(w1 @ f)) + prep (pc copy, p extract, wwA bf16 frag pack) ----------
// wwAbf fragment order: frag=(otile*4+ks)*64+lane, elem j; A[o=otile*16+(lane&15)][c=ks*32+(lane>>4)*8+j]
__global__ __launch_bounds__(256) void k_f1(const float* __restrict__ f, const float* __restrict__ w1,
                     const float* __restrict__ g1, const float* __restrict__ b1,
                     const float* __restrict__ pc, const float* __restrict__ ww,
                     float* __restrict__ f1T, float* __restrict__ outPc,
                     float* __restrict__ p, unsigned short* __restrict__ wwAbf)
{
    int tid = threadIdx.x;
    int bid = blockIdx.x;
    {
        int t = bid*256 + tid;
        if (t < BB*NN*6) {
            float v = pc[t];
            outPc[t] = v;
            int d = t % 6;
            if (d < 3) p[(t/6)*3 + d] = v;
        }
        if (t < CO*CO) {
            int o = t >> 7, c = t & 127;
            int otile = o >> 4, m = o & 15;
            int ks = c >> 5, kk = c & 31;
            int lane = m | ((kk >> 3) << 4);
            int j = kk & 7;
            wwAbf[(((otile*4 + ks)*64 + lane)<<3) + j] = f2bf(ww[t]);
        }
    }
    __shared__ float W[CI*CO];           // w1T[c][o]
    for (int i = tid; i < CI*CO; i += 256) {
        int o = i >> 6, c = i & 63;
        W[c*CO + o] = w1[i];
    }
    __syncthreads();
    int b = bid >> 11;
    int n = (bid & 2047)*2 + (tid >> 7);
    int o = tid & 127;
    const float* fb = f + (size_t)b*CI*NN + n;
    float acc = 0.f;
    #pragma unroll 8
    for (int c = 0; c < CI; ++c)
        acc += W[c*CO + o] * fb[(size_t)c*NN];
    float sc = g1[o] / sqrtf(1.00001f);
    f1T[((size_t)b*NN + n)*CO + o] = relu_(acc*sc + b1[o]);
}

// ---------- kernel 2: ball query 1 -> idx (B,N,K) ----------
__global__ void k_bq1(const float* __restrict__ p, int* __restrict__ idx)
{
    int wave = threadIdx.x >> 6;
    int lane = threadIdx.x & 63;
    int q = blockIdx.x*4 + wave;          // 0..8191
    int b = q >> 12;
    int n = q & 4095;
    const float* pb = p + (size_t)b*NN*3;
    float qx = pb[n*3+0], qy = pb[n*3+1], qz = pb[n*3+2];
    float sq = qx*qx + qy*qy + qz*qz;
    const float rsq = (float)(0.15*0.15);
    int cnt = 0, first = 0;
    int* orow = idx + (size_t)q*KK;
    for (int chunk = 0; chunk < 64; ++chunk) {
        int s = chunk*64 + lane;
        float sx = pb[s*3+0], sy = pb[s*3+1], sz = pb[s*3+2];
        float ss  = sx*sx + sy*sy + sz*sz;
        float dot = qx*sx + qy*sy + qz*sz;
        float d2 = (sq + ss) - 2.0f*dot;
        unsigned long long m = __ballot(d2 < rsq);
        while (m && cnt < KK) {
            int pos = __ffsll((unsigned long long)m) - 1;
            int sidx = chunk*64 + pos;
            if (cnt == 0) first = sidx;
            if (lane == 0) orow[cnt] = sidx;
            ++cnt;
            m &= m - 1;
        }
        if (cnt >= KK) break;
    }
    if (lane == 0)
        for (int j = cnt; j < KK; ++j) orow[j] = first;
}

// ---------- kernel 3: dp[b,d,n,k] = p[b,idx,d] - p[b,n,d] ----------
__global__ void k_mkdp(const float* __restrict__ p, const int* __restrict__ idx,
                       float* __restrict__ dp)
{
    int t = blockIdx.x*blockDim.x + threadIdx.x;   // 196608 exact
    int k = t % KK;
    int n = (t / KK) % NN;
    int b = t / (NN*KK);
    int j = idx[t];
    const float* pb = p + (size_t)b*NN*3;
    #pragma unroll
    for (int d = 0; d < 3; ++d)
        dp[(((size_t)b*3 + d)*NN + n)*KK + k] = pb[j*3+d] - pb[n*3+d];
}

// ---------- kernel 4: FPS permutation on each 24x3 row ----------
__global__ __launch_bounds__(64) void k_fps(const float* __restrict__ dp, float* __restrict__ ndp)
{
    __shared__ float P[3][KK][64];
    int t = threadIdx.x;
    int row = blockIdx.x*64 + t;         // < 8192
    const float* src = dp + (size_t)row*72;
    float px[KK], py[KK], pz[KK];
    #pragma unroll
    for (int k = 0; k < KK; ++k) {
        float x = src[k*3+0], y = src[k*3+1], z = src[k*3+2];
        px[k]=x; py[k]=y; pz[k]=z;
        P[0][k][t]=x; P[1][k][t]=y; P[2][k][t]=z;
    }
    float* dst = ndp + (size_t)row*72;
    dst[0] = px[0]; dst[1] = py[0]; dst[2] = pz[0];
    float dists[KK];
    #pragma unroll
    for (int k=0;k<KK;++k) dists[k]=1e10f;
    int last = 0;
    for (int j = 1; j < KK; ++j) {
        float lx = P[0][last][t], ly = P[1][last][t], lz = P[2][last][t];
        float best = -3.4e38f; int bk = 0;
        #pragma unroll
        for (int k = 0; k < KK; ++k) {
            float dx = px[k]-lx, dy = py[k]-ly, dz = pz[k]-lz;
            float d = dx*dx + dy*dy + dz*dz;
            float nd = fminf(dists[k], d);
            dists[k] = nd;
            if (nd > best) { best = nd; bk = k; }   // strict >: first-occurrence argmax
        }
        dst[j*3+0] = P[0][bk][t];
        dst[j*3+1] = P[1][bk][t];
        dst[j*3+2] = P[2][bk][t];
        last = bk;
    }
}

// ---------- kernel 5: displacement MLP (3->32->16->3) + residual -> q2 ----------
__global__ void k_mlp(const float* __restrict__ ndp,
                      const float* __restrict__ wd1, const float* __restrict__ gd1, const float* __restrict__ bd1,
                      const float* __restrict__ wd2, const float* __restrict__ gd2, const float* __restrict__ bd2,
                      const float* __restrict__ wd3, const float* __restrict__ gd3, const float* __restrict__ bd3,
                      float* __restrict__ q2)
{
    __shared__ float W1[96], S1[32], B1s[32], W2[512], S2[16], B2s[16], W3[48], S3[3], B3s[3];
    int tid = threadIdx.x;
    const float inv = sqrtf(1.00001f);
    for (int i = tid; i < 96;  i += blockDim.x) W1[i]=wd1[i];
    for (int i = tid; i < 512; i += blockDim.x) W2[i]=wd2[i];
    for (int i = tid; i < 48;  i += blockDim.x) W3[i]=wd3[i];
    if (tid < 32) { S1[tid]=gd1[tid]/inv; B1s[tid]=bd1[tid]; }
    if (tid >= 32 && tid < 48) { int c=tid-32; S2[c]=gd2[c]/inv; B2s[c]=bd2[c]; }
    if (tid >= 48 && tid < 51) { int c=tid-48; S3[c]=gd3[c]/inv; B3s[c]=bd3[c]; }
    __syncthreads();
    int t = blockIdx.x*blockDim.x + tid;   // 196608 exact
    int k = t % KK, n = (t/KK)%NN, b = t/(NN*KK);
    size_t base = (((size_t)b*3)*NN + n)*KK + k;
    float x0 = ndp[base], x1 = ndp[base + NKK], x2 = ndp[base + 2*(size_t)NKK];
    float h1[32];
    #pragma unroll
    for (int o = 0; o < 32; ++o)
        h1[o] = relu_((W1[o*3+0]*x0 + W1[o*3+1]*x1 + W1[o*3+2]*x2)*S1[o] + B1s[o]);
    float h2[16];
    #pragma unroll
    for (int o = 0; o < 16; ++o) {
        float a = 0.f;
        #pragma unroll
        for (int c = 0; c < 32; ++c) a += W2[o*32+c]*h1[c];
        h2[o] = relu_(a*S2[o] + B2s[o]);
    }
    float xv[3] = {x0, x1, x2};
    #pragma unroll
    for (int d = 0; d < 3; ++d) {
        float a = 0.f;
        #pragma unroll
        for (int c = 0; c < 16; ++c) a += W3[d*16+c]*h2[c];
        q2[base + (size_t)d*NKK] = xv[d] + (a*S3[d] + B3s[d]);
    }
}

// ---------- kernel 6: ball query 2 (k=1) + dp2 = s2[j2] - q2 ----------
__global__ void k_bq2(const float* __restrict__ dpf, const float* __restrict__ q2f,
                      int* __restrict__ idx2, float* __restrict__ dp2)
{
    int t = blockIdx.x*blockDim.x + threadIdx.x;   // 196608 exact
    int g = t / KK, kq = t % KK;
    const float* srow = dpf + (size_t)g*72;
    const float* qp   = q2f + (size_t)g*72 + kq*3;
    float qx=qp[0], qy=qp[1], qz=qp[2];
    float sq = qx*qx + qy*qy + qz*qz;
    const float rsq = (float)(0.15*0.15);
    int j2 = 0;
    for (int s = 0; s < KK; ++s) {
        float sx=srow[s*3+0], sy=srow[s*3+1], sz=srow[s*3+2];
        float ss  = sx*sx + sy*sy + sz*sz;
        float dot = qx*sx + qy*sy + qz*sz;
        float d2 = (sq + ss) - 2.0f*dot;
        if (d2 < rsq) { j2 = s; break; }
    }
    idx2[t] = j2;
    float* drow = dp2 + (size_t)g*72;
    drow[0*KK + kq] = srow[j2*3+0] - qx;
    drow[1*KK + kq] = srow[j2*3+1] - qy;
    drow[2*KK + kq] = srow[j2*3+2] - qz;
}

// ---------- kernel 7: fused gather + MFMA conv + softmax + pe + fout ----------
// Block: 2 n's (same n>>7 band). Phases:
//   gather G[c][kk] (f32, coalesced) -> permute to Fbf[col=nl*24+k][c] bf16, XOR-swizzled.
//   MFMA: M[o][col] = sum_c ww[o][c]*F[col][c]; wave w owns o in [32w,32w+32).
//   M[col][o] f32 in LDS (overlays G). Epilogue = R3's, reading M.
__global__ __launch_bounds__(256, 4) void k_final(
    const float* __restrict__ f1T, const int* __restrict__ idx, const int* __restrict__ idx2,
    const float* __restrict__ dp2, const unsigned short* __restrict__ wwAbf,
    const float* __restrict__ gw, const float* __restrict__ bw,
    const float* __restrict__ wc2, const float* __restrict__ gc2, const float* __restrict__ bc2,
    float* __restrict__ fout, float* __restrict__ pe)
{
    __shared__ float GM[48*132];            // union: G[c][kk] stride25 (3200 f) | M[col][o] stride132 (6336 f)
    __shared__ unsigned short Fbf[48*128];  // bf16 [col][c], byte ^= (col&7)<<4
    __shared__ float Ds[2][3][KK];
    __shared__ int   IRs[2][KK];
    int tid = threadIdx.x;
    int bid = blockIdx.x;
    int b = bid >> 11;
    int n0 = (bid & 2047)*2;

    // phase 0
    if (tid < 48) {
        int nl = tid/24, kk = tid%24;
        IRs[nl][kk] = idx[((size_t)b*NN + (n0+nl))*KK + kk];
    }
    if (tid >= 64 && tid < 208) {
        int u = tid-64; int nl = u/72, r = u%72, d = r/24, k = r%24;
        Ds[nl][d][k] = dp2[(((size_t)b*3 + d)*NN + (n0+nl))*KK + k];
    }
    int c = tid & 127, kh = tid >> 7;
    int i2r[12];
    {
        int g = (b*CO + c)*32 + (n0 >> 7);
        const int4* i4 = (const int4*)(idx2 + (size_t)g*KK) + kh*3;
        int4 a = i4[0], bq = i4[1], cq4 = i4[2];
        i2r[0]=a.x; i2r[1]=a.y; i2r[2]=a.z; i2r[3]=a.w;
        i2r[4]=bq.x; i2r[5]=bq.y; i2r[6]=bq.z; i2r[7]=bq.w;
        i2r[8]=cq4.x; i2r[9]=cq4.y; i2r[10]=cq4.z; i2r[11]=cq4.w;
    }
    // A fragments (independent of LDS phases; 8 coalesced dwordx4)
    int wv = tid >> 6, l = tid & 63;
    const short8* wwA8 = (const short8*)wwAbf;
    short8 Af[2][4];
    #pragma unroll
    for (int ot = 0; ot < 2; ++ot)
        #pragma unroll
        for (int ks = 0; ks < 4; ++ks)
            Af[ot][ks] = wwA8[((wv*2 + ot)*4 + ks)*64 + l];
    __syncthreads();

    // gather + permute per n
    const float* basep = f1T + (size_t)b*NN*CO + c;
    #pragma unroll
    for (int nl = 0; nl < 2; ++nl) {
        #pragma unroll
        for (int j = 0; j < 12; ++j) {
            int kk = kh*12 + j;
            GM[c*25 + kk] = basep[(size_t)IRs[nl][kk]*CO];
        }
        __syncthreads();
        #pragma unroll
        for (int j = 0; j < 12; ++j) {
            int col = nl*24 + kh*12 + j;
            unsigned int boff = (unsigned)((col*256 + c*2) ^ ((col&7)<<4));
            *(unsigned short*)((char*)Fbf + boff) = f2bf(GM[c*25 + i2r[j]]);
        }
        __syncthreads();
    }

    // MFMA: wave wv -> o tiles {2wv, 2wv+1}; 3 col-tiles; 4 k-steps
    {
        f32x4 acc[2][3];
        #pragma unroll
        for (int ot=0;ot<2;++ot)
            #pragma unroll
            for (int ct=0;ct<3;++ct)
                acc[ot][ct] = (f32x4){0.f,0.f,0.f,0.f};
        int row_l = l & 15, kc_l = (l >> 4) << 3;   // 8-elem c-chunk base
        #pragma unroll
        for (int ct = 0; ct < 3; ++ct) {
            int row = ct*16 + row_l;
            #pragma unroll
            for (int ks = 0; ks < 4; ++ks) {
                unsigned int boff = (unsigned)((row*256 + (ks*32 + kc_l)*2) ^ ((row&7)<<4));
                short8 Bf = *(const short8*)((const char*)Fbf + boff);
                acc[0][ct] = __builtin_amdgcn_mfma_f32_16x16x32_bf16(Af[0][ks], Bf, acc[0][ct], 0,0,0);
                acc[1][ct] = __builtin_amdgcn_mfma_f32_16x16x32_bf16(Af[1][ks], Bf, acc[1][ct], 0,0,0);
            }
        }
        // write M[col][o] (overlays G; all G reads completed before last sync)
        #pragma unroll
        for (int ot = 0; ot < 2; ++ot) {
            int o = wv*32 + ot*16 + ((l>>4)<<2);
            #pragma unroll
            for (int ct = 0; ct < 3; ++ct) {
                int col = ct*16 + (l & 15);
                *(f32x4*)&GM[col*132 + o] = acc[ot][ct];
            }
        }
    }
    __syncthreads();

    // epilogue (R3 structure, conv results from M)
    int op = (tid & 127) >> 1, half = tid & 1, nl = tid >> 7;
    int k0 = half*12;
    int o0 = op*2;
    int n  = n0 + nl;
    int colb = nl*24 + k0;
    float a0[12], a1[12];
    #pragma unroll
    for (int j = 0; j < 12; ++j) {
        float2 m2 = *(const float2*)&GM[(colb+j)*132 + o0];
        a0[j] = m2.x; a1[j] = m2.y;
    }
    const float inv = sqrtf(1.00001f);
    float sw0 = gw[o0]/inv,   bw0 = bw[o0];
    float sw1 = gw[o0+1]/inv, bw1 = bw[o0+1];
    float pev0[12], pev1[12];
    {
        float wa0=wc2[o0*3], wa1=wc2[o0*3+1], wa2=wc2[o0*3+2];
        float wb0=wc2[o0*3+3], wb1=wc2[o0*3+4], wb2=wc2[o0*3+5];
        float sca = gc2[o0]/inv,   bca = bc2[o0];
        float scb = gc2[o0+1]/inv, bcb = bc2[o0+1];
        #pragma unroll
        for (int j = 0; j < 12; ++j) {
            float d0 = Ds[nl][0][k0+j], d1 = Ds[nl][1][k0+j], d2 = Ds[nl][2][k0+j];
            pev0[j] = relu_((wa0*d0 + wa1*d1 + wa2*d2)*sca + bca);
            pev1[j] = relu_((wb0*d0 + wb1*d1 + wb2*d2)*scb + bcb);
        }
    }
    float m0 = -3.4e38f, m1 = -3.4e38f;
    #pragma unroll
    for (int j=0;j<12;++j){
        a0[j] = a0[j]*sw0 + bw0; m0 = fmaxf(m0, a0[j]);
        a1[j] = a1[j]*sw1 + bw1; m1 = fmaxf(m1, a1[j]);
    }
    m0 = fmaxf(m0, __shfl_xor(m0, 1));
    m1 = fmaxf(m1, __shfl_xor(m1, 1));
    float s0 = 0.f, s1 = 0.f;
    #pragma unroll
    for (int j=0;j<12;++j){
        a0[j] = __expf(a0[j]-m0); s0 += a0[j];
        a1[j] = __expf(a1[j]-m1); s1 += a1[j];
    }
    s0 += __shfl_xor(s0, 1);
    s1 += __shfl_xor(s1, 1);
    float rs0 = 1.0f/s0, rs1 = 1.0f/s1;
    float fo0 = -3.4e38f, fo1 = -3.4e38f;
    #pragma unroll
    for (int j=0;j<12;++j){
        unsigned int boff = (unsigned)(((colb+j)*256 + o0*2) ^ (((colb+j)&7)<<4));
        unsigned int v = *(const unsigned int*)((const char*)Fbf + boff);
        float fj0 = __uint_as_float((v & 0xffffu) << 16);
        float fj1 = __uint_as_float((v >> 16) << 16);
        fo0 = fmaxf(fo0, (pev0[j] + fj0)*a0[j]*rs0);
        fo1 = fmaxf(fo1, (pev1[j] + fj1)*a1[j]*rs1);
    }
    fo0 = fmaxf(fo0, __shfl_xor(fo0, 1));
    fo1 = fmaxf(fo1, __shfl_xor(fo1, 1));
    fout[((size_t)b*CO + o0+half)*NN + n] = half ? fo1 : fo0;
    float* pr0 = pe + (((size_t)b*CO + o0)*NN + n)*KK + k0;
    float* pr1 = pe + (((size_t)b*CO + o0+1)*NN + n)*KK + k0;
    #pragma unroll
    for (int q4 = 0; q4 < 3; ++q4) {
        float4 v0, v1;
        v0.x=pev0[q4*4+0]; v0.y=pev0[q4*4+1]; v0.z=pev0[q4*4+2]; v0.w=pev0[q4*4+3];
        v1.x=pev1[q4*4+0]; v1.y=pev1[q4*4+1]; v1.z=pev1[q4*4+2]; v1.w=pev1[q4*4+3];
        ((float4*)pr0)[q4] = v0;
        ((float4*)pr1)[q4] = v1;
    }
}

extern "C" void kernel_launch(void* const* d_in, const int* in_sizes, int n_in,
                              void* d_out, int out_size, void* d_ws, size_t ws_size,
                              hipStream_t stream)
{
    const float* pc  = (const float*)d_in[0];
    const float* f   = (const float*)d_in[1];
    const float* w1  = (const float*)d_in[3];
    const float* g1  = (const float*)d_in[4];
    const float* b1  = (const float*)d_in[5];
    const float* wd1 = (const float*)d_in[6];
    const float* gd1 = (const float*)d_in[7];
    const float* bd1 = (const float*)d_in[8];
    const float* wd2 = (const float*)d_in[9];
    const float* gd2 = (const float*)d_in[10];
    const float* bd2 = (const float*)d_in[11];
    const float* wd3 = (const float*)d_in[12];
    const float* gd3 = (const float*)d_in[13];
    const float* bd3 = (const float*)d_in[14];
    const float* ww  = (const float*)d_in[15];
    const float* gw  = (const float*)d_in[16];
    const float* bw  = (const float*)d_in[17];
    const float* wc2 = (const float*)d_in[18];
    const float* gc2 = (const float*)d_in[19];
    const float* bc2 = (const float*)d_in[20];

    float* out     = (float*)d_out;
    float* outPc   = out;                               // 49152
    float* outFout = out + 49152;                       // 1048576
    float* outPe   = out + 49152 + 1048576;             // 25165824

    char* ws = (char*)d_ws;
    size_t off = 0;
    auto alloc = [&](size_t bytes)->void* {
        void* q = ws + off; off += (bytes + 255) & ~(size_t)255; return q;
    };
    float* p    = (float*)alloc((size_t)BB*NN*3*4);
    float* f1T  = (float*)alloc((size_t)BB*NN*CO*4);
    int*   idx  = (int*)  alloc((size_t)BB*NN*KK*4);
    float* dpf  = (float*)alloc((size_t)BB*3*NN*KK*4);
    float* ndp  = (float*)alloc((size_t)BB*3*NN*KK*4);
    float* q2f  = (float*)alloc((size_t)BB*3*NN*KK*4);
    int*   idx2 = (int*)  alloc((size_t)GQ*KK*4);
    float* dp2  = (float*)alloc((size_t)GQ*72*4);
    unsigned short* wwAbf = (unsigned short*)alloc((size_t)CO*CO*2);

    k_f1   <<<dim3(BB*NN/2), dim3(256), 0, stream>>>(f, w1, g1, b1, pc, ww, f1T, outPc, p, wwAbf);
    k_bq1  <<<dim3(GQ/4), dim3(256), 0, stream>>>(p, idx);
    k_mkdp <<<dim3((BB*NN*KK)/256), dim3(256), 0, stream>>>(p, idx, dpf);
    k_fps  <<<dim3(GQ/64), dim3(64), 0, stream>>>(dpf, ndp);
    k_mlp  <<<dim3((BB*NN*KK)/256), dim3(256), 0, stream>>>(ndp, wd1,gd1,bd1, wd2,gd2,bd2, wd3,gd3,bd3, q2f);
    k_bq2  <<<dim3((GQ*KK)/256), dim3(256), 0, stream>>>(dpf, q2f, idx2, dp2);
    k_final<<<dim3(BB*NN/2), dim3(256), 0, stream>>>(f1T, idx, idx2, dp2, wwAbf, gw, bw, wc2, gc2, bc2, outFout, outPe);
}

// Round 5
// 127.471 us; speedup vs baseline: 2.9312x; 1.3974x over previous
//
#include <hip/hip_runtime.h>
#include <stdint.h>

// SetAbstraction forward, MI355X. B=2, N=4096, CIN=64, COUT=128, K=24.
// R5: k_f1 restructured (pad-129 W staging = conflict-free, 16n/block, f-tile LDS);
// k_fps lane-parallel (shfl argmax, 24 lanes/row). k_final MFMA unchanged from R4.

#define BB 2
#define NN 4096
#define CI 64
#define CO 128
#define KK 24
#define GQ (BB*NN)        // 8192
#define NKK (NN*KK)       // 98304

typedef __attribute__((ext_vector_type(8))) short short8;
typedef __attribute__((ext_vector_type(4))) float f32x4;

__device__ __forceinline__ float relu_(float x){ return fmaxf(x, 0.0f); }
__device__ __forceinline__ unsigned short f2bf(float x){
    unsigned int u = __float_as_uint(x);
    return (unsigned short)((u + 0x7FFFu + ((u>>16)&1u)) >> 16);
}

// ---------- kernel 1: f1T[b][n][o] = relu(bn(w1 @ f)) + prep ----------
// 16 n per block, grid 512. W staged [c][129] (conflict-free both ways),
// f tile [64][16] float4-dense. c-order of accumulation identical to before.
__global__ __launch_bounds__(256) void k_f1(const float* __restrict__ f, const float* __restrict__ w1,
                     const float* __restrict__ g1, const float* __restrict__ b1,
                     const float* __restrict__ pc, const float* __restrict__ ww,
                     float* __restrict__ f1T, float* __restrict__ outPc,
                     float* __restrict__ p, unsigned short* __restrict__ wwAbf)
{
    int tid = threadIdx.x;
    int bid = blockIdx.x;
    {   // prep (grid 512 covers: 49152/256=192 blocks, 16384/256=64 blocks)
        int t = bid*256 + tid;
        if (t < BB*NN*6) {
            float v = pc[t];
            outPc[t] = v;
            int d = t % 6;
            if (d < 3) p[(t/6)*3 + d] = v;
        }
        if (t < CO*CO) {
            int o = t >> 7, c = t & 127;
            int otile = o >> 4, m = o & 15;
            int ks = c >> 5, kk = c & 31;
            int lane = m | ((kk >> 3) << 4);
            int j = kk & 7;
            wwAbf[(((otile*4 + ks)*64 + lane)<<3) + j] = f2bf(ww[t]);
        }
    }
    __shared__ float W[CI*129];          // [c][129]: bank=(c+o)%32 conflict-free
    __shared__ float ft[CI*16];          // [c][16] dense
    for (int i = tid; i < CI*CO; i += 256) {
        int o = i >> 6, c = i & 63;
        W[c*129 + o] = w1[i];
    }
    int b = bid >> 8;
    int n0 = (bid & 255) * 16;
    {
        int c = tid >> 2, nn = (tid & 3) * 4;
        float4 v = *(const float4*)(f + (size_t)b*CI*NN + (size_t)c*NN + n0 + nn);
        *(float4*)&ft[c*16 + nn] = v;
    }
    __syncthreads();
    int o = tid & 127, g = tid >> 7;
    float acc[8];
    #pragma unroll
    for (int j = 0; j < 8; ++j) acc[j] = 0.f;
    const float* ftg = ft + g*8;
    #pragma unroll 8
    for (int c = 0; c < CI; ++c) {
        float w = W[c*129 + o];
        float4 fa = *(const float4*)&ftg[c*16];
        float4 fb4 = *(const float4*)&ftg[c*16 + 4];
        acc[0] += w*fa.x;  acc[1] += w*fa.y;  acc[2] += w*fa.z;  acc[3] += w*fa.w;
        acc[4] += w*fb4.x; acc[5] += w*fb4.y; acc[6] += w*fb4.z; acc[7] += w*fb4.w;
    }
    float sc = g1[o] / sqrtf(1.00001f);
    float bo = b1[o];
    #pragma unroll
    for (int j = 0; j < 8; ++j) {
        int n = n0 + g*8 + j;
        f1T[((size_t)b*NN + n)*CO + o] = relu_(acc[j]*sc + bo);
    }
}

// ---------- kernel 2: ball query 1 -> idx (B,N,K) ----------
__global__ void k_bq1(const float* __restrict__ p, int* __restrict__ idx)
{
    int wave = threadIdx.x >> 6;
    int lane = threadIdx.x & 63;
    int q = blockIdx.x*4 + wave;          // 0..8191
    int b = q >> 12;
    int n = q & 4095;
    const float* pb = p + (size_t)b*NN*3;
    float qx = pb[n*3+0], qy = pb[n*3+1], qz = pb[n*3+2];
    float sq = qx*qx + qy*qy + qz*qz;
    const float rsq = (float)(0.15*0.15);
    int cnt = 0, first = 0;
    int* orow = idx + (size_t)q*KK;
    for (int chunk = 0; chunk < 64; ++chunk) {
        int s = chunk*64 + lane;
        float sx = pb[s*3+0], sy = pb[s*3+1], sz = pb[s*3+2];
        float ss  = sx*sx + sy*sy + sz*sz;
        float dot = qx*sx + qy*sy + qz*sz;
        float d2 = (sq + ss) - 2.0f*dot;
        unsigned long long m = __ballot(d2 < rsq);
        while (m && cnt < KK) {
            int pos = __ffsll((unsigned long long)m) - 1;
            int sidx = chunk*64 + pos;
            if (cnt == 0) first = sidx;
            if (lane == 0) orow[cnt] = sidx;
            ++cnt;
            m &= m - 1;
        }
        if (cnt >= KK) break;
    }
    if (lane == 0)
        for (int j = cnt; j < KK; ++j) orow[j] = first;
}

// ---------- kernel 3: dp[b,d,n,k] = p[b,idx,d] - p[b,n,d] ----------
__global__ void k_mkdp(const float* __restrict__ p, const int* __restrict__ idx,
                       float* __restrict__ dp)
{
    int t = blockIdx.x*blockDim.x + threadIdx.x;   // 196608 exact
    int k = t % KK;
    int n = (t / KK) % NN;
    int b = t / (NN*KK);
    int j = idx[t];
    const float* pb = p + (size_t)b*NN*3;
    #pragma unroll
    for (int d = 0; d < 3; ++d)
        dp[(((size_t)b*3 + d)*NN + n)*KK + k] = pb[j*3+d] - pb[n*3+d];
}

// ---------- kernel 4: FPS permutation, lane-parallel (32 lanes/row, 24 active) ----------
__global__ __launch_bounds__(256) void k_fps(const float* __restrict__ dp, float* __restrict__ ndp)
{
    int tid = threadIdx.x;
    int lane = tid & 31;                 // = k
    int row = blockIdx.x*8 + (tid >> 5); // 8 rows/block, grid 1024
    const float* src = dp + (size_t)row*72;
    float px = 0.f, py = 0.f, pz = 0.f, dist;
    if (lane < KK) {
        px = src[lane*3+0]; py = src[lane*3+1]; pz = src[lane*3+2];
        dist = 1e10f;
    } else {
        dist = -3.4e38f;                 // idle lanes never win argmax
    }
    float* dst = ndp + (size_t)row*72;
    if (lane == 0) { dst[0] = px; dst[1] = py; dst[2] = pz; }
    int last = 0;
    for (int j = 1; j < KK; ++j) {
        float lx = __shfl(px, last, 32);
        float ly = __shfl(py, last, 32);
        float lz = __shfl(pz, last, 32);
        float dx = px-lx, dy = py-ly, dz = pz-lz;
        float d = dx*dx + dy*dy + dz*dz;
        dist = fminf(dist, d);           // idle: stays -inf
        float val = dist; int idx = lane;
        #pragma unroll
        for (int off = 16; off > 0; off >>= 1) {
            float ov = __shfl_xor(val, off, 32);
            int   oi = __shfl_xor(idx, off, 32);
            if (ov > val || (ov == val && oi < idx)) { val = ov; idx = oi; }
        }                                // all lanes agree: max val, first index
        if (lane == idx) { dst[j*3+0] = px; dst[j*3+1] = py; dst[j*3+2] = pz; }
        last = idx;
    }
}

// ---------- kernel 5: displacement MLP (3->32->16->3) + residual -> q2 ----------
__global__ void k_mlp(const float* __restrict__ ndp,
                      const float* __restrict__ wd1, const float* __restrict__ gd1, const float* __restrict__ bd1,
                      const float* __restrict__ wd2, const float* __restrict__ gd2, const float* __restrict__ bd2,
                      const float* __restrict__ wd3, const float* __restrict__ gd3, const float* __restrict__ bd3,
                      float* __restrict__ q2)
{
    __shared__ float W1[96], S1[32], B1s[32], W2[512], S2[16], B2s[16], W3[48], S3[3], B3s[3];
    int tid = threadIdx.x;
    const float inv = sqrtf(1.00001f);
    for (int i = tid; i < 96;  i += blockDim.x) W1[i]=wd1[i];
    for (int i = tid; i < 512; i += blockDim.x) W2[i]=wd2[i];
    for (int i = tid; i < 48;  i += blockDim.x) W3[i]=wd3[i];
    if (tid < 32) { S1[tid]=gd1[tid]/inv; B1s[tid]=bd1[tid]; }
    if (tid >= 32 && tid < 48) { int c=tid-32; S2[c]=gd2[c]/inv; B2s[c]=bd2[c]; }
    if (tid >= 48 && tid < 51) { int c=tid-48; S3[c]=gd3[c]/inv; B3s[c]=bd3[c]; }
    __syncthreads();
    int t = blockIdx.x*blockDim.x + tid;   // 196608 exact
    int k = t % KK, n = (t/KK)%NN, b = t/(NN*KK);
    size_t base = (((size_t)b*3)*NN + n)*KK + k;
    float x0 = ndp[base], x1 = ndp[base + NKK], x2 = ndp[base + 2*(size_t)NKK];
    float h1[32];
    #pragma unroll
    for (int o = 0; o < 32; ++o)
        h1[o] = relu_((W1[o*3+0]*x0 + W1[o*3+1]*x1 + W1[o*3+2]*x2)*S1[o] + B1s[o]);
    float h2[16];
    #pragma unroll
    for (int o = 0; o < 16; ++o) {
        float a = 0.f;
        #pragma unroll
        for (int c = 0; c < 32; ++c) a += W2[o*32+c]*h1[c];
        h2[o] = relu_(a*S2[o] + B2s[o]);
    }
    float xv[3] = {x0, x1, x2};
    #pragma unroll
    for (int d = 0; d < 3; ++d) {
        float a = 0.f;
        #pragma unroll
        for (int c = 0; c < 16; ++c) a += W3[d*16+c]*h2[c];
        q2[base + (size_t)d*NKK] = xv[d] + (a*S3[d] + B3s[d]);
    }
}

// ---------- kernel 6: ball query 2 (k=1) + dp2 = s2[j2] - q2 ----------
__global__ void k_bq2(const float* __restrict__ dpf, const float* __restrict__ q2f,
                      int* __restrict__ idx2, float* __restrict__ dp2)
{
    int t = blockIdx.x*blockDim.x + threadIdx.x;   // 196608 exact
    int g = t / KK, kq = t % KK;
    const float* srow = dpf + (size_t)g*72;
    const float* qp   = q2f + (size_t)g*72 + kq*3;
    float qx=qp[0], qy=qp[1], qz=qp[2];
    float sq = qx*qx + qy*qy + qz*qz;
    const float rsq = (float)(0.15*0.15);
    int j2 = 0;
    for (int s = 0; s < KK; ++s) {
        float sx=srow[s*3+0], sy=srow[s*3+1], sz=srow[s*3+2];
        float ss  = sx*sx + sy*sy + sz*sz;
        float dot = qx*sx + qy*sy + qz*sz;
        float d2 = (sq + ss) - 2.0f*dot;
        if (d2 < rsq) { j2 = s; break; }
    }
    idx2[t] = j2;
    float* drow = dp2 + (size_t)g*72;
    drow[0*KK + kq] = srow[j2*3+0] - qx;
    drow[1*KK + kq] = srow[j2*3+1] - qy;
    drow[2*KK + kq] = srow[j2*3+2] - qz;
}

// ---------- kernel 7: fused gather + MFMA conv + softmax + pe + fout ----------
__global__ __launch_bounds__(256, 4) void k_final(
    const float* __restrict__ f1T, const int* __restrict__ idx, const int* __restrict__ idx2,
    const float* __restrict__ dp2, const unsigned short* __restrict__ wwAbf,
    const float* __restrict__ gw, const float* __restrict__ bw,
    const float* __restrict__ wc2, const float* __restrict__ gc2, const float* __restrict__ bc2,
    float* __restrict__ fout, float* __restrict__ pe)
{
    __shared__ float GM[48*132];            // union: G[c][kk] stride25 | M[col][o] stride132
    __shared__ unsigned short Fbf[48*128];  // bf16 [col][c], byte ^= (col&7)<<4
    __shared__ float Ds[2][3][KK];
    __shared__ int   IRs[2][KK];
    int tid = threadIdx.x;
    int bid = blockIdx.x;
    int b = bid >> 11;
    int n0 = (bid & 2047)*2;

    if (tid < 48) {
        int nl = tid/24, kk = tid%24;
        IRs[nl][kk] = idx[((size_t)b*NN + (n0+nl))*KK + kk];
    }
    if (tid >= 64 && tid < 208) {
        int u = tid-64; int nl = u/72, r = u%72, d = r/24, k = r%24;
        Ds[nl][d][k] = dp2[(((size_t)b*3 + d)*NN + (n0+nl))*KK + k];
    }
    int c = tid & 127, kh = tid >> 7;
    int i2r[12];
    {
        int g = (b*CO + c)*32 + (n0 >> 7);
        const int4* i4 = (const int4*)(idx2 + (size_t)g*KK) + kh*3;
        int4 a = i4[0], bq = i4[1], cq4 = i4[2];
        i2r[0]=a.x; i2r[1]=a.y; i2r[2]=a.z; i2r[3]=a.w;
        i2r[4]=bq.x; i2r[5]=bq.y; i2r[6]=bq.z; i2r[7]=bq.w;
        i2r[8]=cq4.x; i2r[9]=cq4.y; i2r[10]=cq4.z; i2r[11]=cq4.w;
    }
    int wv = tid >> 6, l = tid & 63;
    const short8* wwA8 = (const short8*)wwAbf;
    short8 Af[2][4];
    #pragma unroll
    for (int ot = 0; ot < 2; ++ot)
        #pragma unroll
        for (int ks = 0; ks < 4; ++ks)
            Af[ot][ks] = wwA8[((wv*2 + ot)*4 + ks)*64 + l];
    __syncthreads();

    const float* basep = f1T + (size_t)b*NN*CO + c;
    #pragma unroll
    for (int nl = 0; nl < 2; ++nl) {
        #pragma unroll
        for (int j = 0; j < 12; ++j) {
            int kk = kh*12 + j;
            GM[c*25 + kk] = basep[(size_t)IRs[nl][kk]*CO];
        }
        __syncthreads();
        #pragma unroll
        for (int j = 0; j < 12; ++j) {
            int col = nl*24 + kh*12 + j;
            unsigned int boff = (unsigned)((col*256 + c*2) ^ ((col&7)<<4));
            *(unsigned short*)((char*)Fbf + boff) = f2bf(GM[c*25 + i2r[j]]);
        }
        __syncthreads();
    }

    {
        f32x4 acc[2][3];
        #pragma unroll
        for (int ot=0;ot<2;++ot)
            #pragma unroll
            for (int ct=0;ct<3;++ct)
                acc[ot][ct] = (f32x4){0.f,0.f,0.f,0.f};
        int row_l = l & 15, kc_l = (l >> 4) << 3;
        #pragma unroll
        for (int ct = 0; ct < 3; ++ct) {
            int row = ct*16 + row_l;
            #pragma unroll
            for (int ks = 0; ks < 4; ++ks) {
                unsigned int boff = (unsigned)((row*256 + (ks*32 + kc_l)*2) ^ ((row&7)<<4));
                short8 Bf = *(const short8*)((const char*)Fbf + boff);
                acc[0][ct] = __builtin_amdgcn_mfma_f32_16x16x32_bf16(Af[0][ks], Bf, acc[0][ct], 0,0,0);
                acc[1][ct] = __builtin_amdgcn_mfma_f32_16x16x32_bf16(Af[1][ks], Bf, acc[1][ct], 0,0,0);
            }
        }
        #pragma unroll
        for (int ot = 0; ot < 2; ++ot) {
            int o = wv*32 + ot*16 + ((l>>4)<<2);
            #pragma unroll
            for (int ct = 0; ct < 3; ++ct) {
                int col = ct*16 + (l & 15);
                *(f32x4*)&GM[col*132 + o] = acc[ot][ct];
            }
        }
    }
    __syncthreads();

    int op = (tid & 127) >> 1, half = tid & 1, nl = tid >> 7;
    int k0 = half*12;
    int o0 = op*2;
    int n  = n0 + nl;
    int colb = nl*24 + k0;
    float a0[12], a1[12];
    #pragma unroll
    for (int j = 0; j < 12; ++j) {
        float2 m2 = *(const float2*)&GM[(colb+j)*132 + o0];
        a0[j] = m2.x; a1[j] = m2.y;
    }
    const float inv = sqrtf(1.00001f);
    float sw0 = gw[o0]/inv,   bw0 = bw[o0];
    float sw1 = gw[o0+1]/inv, bw1 = bw[o0+1];
    float pev0[12], pev1[12];
    {
        float wa0=wc2[o0*3], wa1=wc2[o0*3+1], wa2=wc2[o0*3+2];
        float wb0=wc2[o0*3+3], wb1=wc2[o0*3+4], wb2=wc2[o0*3+5];
        float sca = gc2[o0]/inv,   bca = bc2[o0];
        float scb = gc2[o0+1]/inv, bcb = bc2[o0+1];
        #pragma unroll
        for (int j = 0; j < 12; ++j) {
            float d0 = Ds[nl][0][k0+j], d1 = Ds[nl][1][k0+j], d2 = Ds[nl][2][k0+j];
            pev0[j] = relu_((wa0*d0 + wa1*d1 + wa2*d2)*sca + bca);
            pev1[j] = relu_((wb0*d0 + wb1*d1 + wb2*d2)*scb + bcb);
        }
    }
    float m0 = -3.4e38f, m1 = -3.4e38f;
    #pragma unroll
    for (int j=0;j<12;++j){
        a0[j] = a0[j]*sw0 + bw0; m0 = fmaxf(m0, a0[j]);
        a1[j] = a1[j]*sw1 + bw1; m1 = fmaxf(m1, a1[j]);
    }
    m0 = fmaxf(m0, __shfl_xor(m0, 1));
    m1 = fmaxf(m1, __shfl_xor(m1, 1));
    float s0 = 0.f, s1 = 0.f;
    #pragma unroll
    for (int j=0;j<12;++j){
        a0[j] = __expf(a0[j]-m0); s0 += a0[j];
        a1[j] = __expf(a1[j]-m1); s1 += a1[j];
    }
    s0 += __shfl_xor(s0, 1);
    s1 += __shfl_xor(s1, 1);
    float rs0 = 1.0f/s0, rs1 = 1.0f/s1;
    float fo0 = -3.4e38f, fo1 = -3.4e38f;
    #pragma unroll
    for (int j=0;j<12;++j){
        unsigned int boff = (unsigned)(((colb+j)*256 + o0*2) ^ (((colb+j)&7)<<4));
        unsigned int v = *(const unsigned int*)((const char*)Fbf + boff);
        float fj0 = __uint_as_float((v & 0xffffu) << 16);
        float fj1 = __uint_as_float((v >> 16) << 16);
        fo0 = fmaxf(fo0, (pev0[j] + fj0)*a0[j]*rs0);
        fo1 = fmaxf(fo1, (pev1[j] + fj1)*a1[j]*rs1);
    }
    fo0 = fmaxf(fo0, __shfl_xor(fo0, 1));
    fo1 = fmaxf(fo1, __shfl_xor(fo1, 1));
    fout[((size_t)b*CO + o0+half)*NN + n] = half ? fo1 : fo0;
    float* pr0 = pe + (((size_t)b*CO + o0)*NN + n)*KK + k0;
    float* pr1 = pe + (((size_t)b*CO + o0+1)*NN + n)*KK + k0;
    #pragma unroll
    for (int q4 = 0; q4 < 3; ++q4) {
        float4 v0, v1;
        v0.x=pev0[q4*4+0]; v0.y=pev0[q4*4+1]; v0.z=pev0[q4*4+2]; v0.w=pev0[q4*4+3];
        v1.x=pev1[q4*4+0]; v1.y=pev1[q4*4+1]; v1.z=pev1[q4*4+2]; v1.w=pev1[q4*4+3];
        ((float4*)pr0)[q4] = v0;
        ((float4*)pr1)[q4] = v1;
    }
}

extern "C" void kernel_launch(void* const* d_in, const int* in_sizes, int n_in,
                              void* d_out, int out_size, void* d_ws, size_t ws_size,
                              hipStream_t stream)
{
    const float* pc  = (const float*)d_in[0];
    const float* f   = (const float*)d_in[1];
    const float* w1  = (const float*)d_in[3];
    const float* g1  = (const float*)d_in[4];
    const float* b1  = (const float*)d_in[5];
    const float* wd1 = (const float*)d_in[6];
    const float* gd1 = (const float*)d_in[7];
    const float* bd1 = (const float*)d_in[8];
    const float* wd2 = (const float*)d_in[9];
    const float* gd2 = (const float*)d_in[10];
    const float* bd2 = (const float*)d_in[11];
    const float* wd3 = (const float*)d_in[12];
    const float* gd3 = (const float*)d_in[13];
    const float* bd3 = (const float*)d_in[14];
    const float* ww  = (const float*)d_in[15];
    const float* gw  = (const float*)d_in[16];
    const float* bw  = (const float*)d_in[17];
    const float* wc2 = (const float*)d_in[18];
    const float* gc2 = (const float*)d_in[19];
    const float* bc2 = (const float*)d_in[20];

    float* out     = (float*)d_out;
    float* outPc   = out;                               // 49152
    float* outFout = out + 49152;                       // 1048576
    float* outPe   = out + 49152 + 1048576;             // 25165824

    char* ws = (char*)d_ws;
    size_t off = 0;
    auto alloc = [&](size_t bytes)->void* {
        void* q = ws + off; off += (bytes + 255) & ~(size_t)255; return q;
    };
    float* p    = (float*)alloc((size_t)BB*NN*3*4);
    float* f1T  = (float*)alloc((size_t)BB*NN*CO*4);
    int*   idx  = (int*)  alloc((size_t)BB*NN*KK*4);
    float* dpf  = (float*)alloc((size_t)BB*3*NN*KK*4);
    float* ndp  = (float*)alloc((size_t)BB*3*NN*KK*4);
    float* q2f  = (float*)alloc((size_t)BB*3*NN*KK*4);
    int*   idx2 = (int*)  alloc((size_t)GQ*KK*4);
    float* dp2  = (float*)alloc((size_t)GQ*72*4);
    unsigned short* wwAbf = (unsigned short*)alloc((size_t)CO*CO*2);

    k_f1   <<<dim3(512), dim3(256), 0, stream>>>(f, w1, g1, b1, pc, ww, f1T, outPc, p, wwAbf);
    k_bq1  <<<dim3(GQ/4), dim3(256), 0, stream>>>(p, idx);
    k_mkdp <<<dim3((BB*NN*KK)/256), dim3(256), 0, stream>>>(p, idx, dpf);
    k_fps  <<<dim3(GQ/8), dim3(256), 0, stream>>>(dpf, ndp);
    k_mlp  <<<dim3((BB*NN*KK)/256), dim3(256), 0, stream>>>(ndp, wd1,gd1,bd1, wd2,gd2,bd2, wd3,gd3,bd3, q2f);
    k_bq2  <<<dim3((GQ*KK)/256), dim3(256), 0, stream>>>(dpf, q2f, idx2, dp2);
    k_final<<<dim3(BB*NN/2), dim3(256), 0, stream>>>(f1T, idx, idx2, dp2, wwAbf, gw, bw, wc2, gc2, bc2, outFout, outPe);
}

// Round 6
// 121.925 us; speedup vs baseline: 3.0645x; 1.0455x over previous
//
#include <hip/hip_runtime.h>
#include <stdint.h>

// SetAbstraction forward, MI355X. B=2, N=4096, CIN=64, COUT=128, K=24.
// R6: k_final 4-barrier dual-n gather; k_geo = fused mkdp+FPS (reg-resident);
// p SoA side copy for bq1 coalescing. MFMA conv & epilogue unchanged from R5 (passing).

#define BB 2
#define NN 4096
#define CI 64
#define CO 128
#define KK 24
#define GQ (BB*NN)        // 8192
#define NKK (NN*KK)       // 98304

typedef __attribute__((ext_vector_type(8))) short short8;
typedef __attribute__((ext_vector_type(4))) float f32x4;

__device__ __forceinline__ float relu_(float x){ return fmaxf(x, 0.0f); }
__device__ __forceinline__ unsigned short f2bf(float x){
    unsigned int u = __float_as_uint(x);
    return (unsigned short)((u + 0x7FFFu + ((u>>16)&1u)) >> 16);
}

// ---------- kernel 1: f1T[b][n][o] = relu(bn(w1 @ f)) + prep ----------
__global__ __launch_bounds__(256) void k_f1(const float* __restrict__ f, const float* __restrict__ w1,
                     const float* __restrict__ g1, const float* __restrict__ b1,
                     const float* __restrict__ pc, const float* __restrict__ ww,
                     float* __restrict__ f1T, float* __restrict__ outPc,
                     float* __restrict__ p, float* __restrict__ pS,
                     unsigned short* __restrict__ wwAbf)
{
    int tid = threadIdx.x;
    int bid = blockIdx.x;
    {   // prep (grid 512 covers 49152 and 16384)
        int t = bid*256 + tid;
        if (t < BB*NN*6) {
            float v = pc[t];
            outPc[t] = v;
            int d = t % 6;
            if (d < 3) {
                int q = t/6;
                p[q*3 + d] = v;
                pS[d*GQ + q] = v;       // SoA: pS[d][b*4096+n]
            }
        }
        if (t < CO*CO) {
            int o = t >> 7, c = t & 127;
            int otile = o >> 4, m = o & 15;
            int ks = c >> 5, kk = c & 31;
            int lane = m | ((kk >> 3) << 4);
            int j = kk & 7;
            wwAbf[(((otile*4 + ks)*64 + lane)<<3) + j] = f2bf(ww[t]);
        }
    }
    __shared__ float W[CI*129];
    __shared__ float ft[CI*16];
    for (int i = tid; i < CI*CO; i += 256) {
        int o = i >> 6, c = i & 63;
        W[c*129 + o] = w1[i];
    }
    int b = bid >> 8;
    int n0 = (bid & 255) * 16;
    {
        int c = tid >> 2, nn = (tid & 3) * 4;
        float4 v = *(const float4*)(f + (size_t)b*CI*NN + (size_t)c*NN + n0 + nn);
        *(float4*)&ft[c*16 + nn] = v;
    }
    __syncthreads();
    int o = tid & 127, g = tid >> 7;
    float acc[8];
    #pragma unroll
    for (int j = 0; j < 8; ++j) acc[j] = 0.f;
    const float* ftg = ft + g*8;
    #pragma unroll 8
    for (int c = 0; c < CI; ++c) {
        float w = W[c*129 + o];
        float4 fa = *(const float4*)&ftg[c*16];
        float4 fb4 = *(const float4*)&ftg[c*16 + 4];
        acc[0] += w*fa.x;  acc[1] += w*fa.y;  acc[2] += w*fa.z;  acc[3] += w*fa.w;
        acc[4] += w*fb4.x; acc[5] += w*fb4.y; acc[6] += w*fb4.z; acc[7] += w*fb4.w;
    }
    float sc = g1[o] / sqrtf(1.00001f);
    float bo = b1[o];
    #pragma unroll
    for (int j = 0; j < 8; ++j) {
        int n = n0 + g*8 + j;
        f1T[((size_t)b*NN + n)*CO + o] = relu_(acc[j]*sc + bo);
    }
}

// ---------- kernel 2: ball query 1 -> idx (B,N,K), SoA point loads ----------
__global__ void k_bq1(const float* __restrict__ pS, int* __restrict__ idx)
{
    int wave = threadIdx.x >> 6;
    int lane = threadIdx.x & 63;
    int q = blockIdx.x*4 + wave;          // 0..8191
    int b = q >> 12;
    int n = q & 4095;
    int boff = b << 12;
    const float* Sx = pS + boff;
    const float* Sy = pS + GQ + boff;
    const float* Sz = pS + 2*GQ + boff;
    float qx = Sx[n], qy = Sy[n], qz = Sz[n];
    float sq = qx*qx + qy*qy + qz*qz;
    const float rsq = (float)(0.15*0.15);
    int cnt = 0, first = 0;
    int* orow = idx + (size_t)q*KK;
    for (int chunk = 0; chunk < 64; ++chunk) {
        int s = chunk*64 + lane;
        float sx = Sx[s], sy = Sy[s], sz = Sz[s];
        float ss  = sx*sx + sy*sy + sz*sz;
        float dot = qx*sx + qy*sy + qz*sz;
        float d2 = (sq + ss) - 2.0f*dot;
        unsigned long long m = __ballot(d2 < rsq);
        while (m && cnt < KK) {
            int pos = __ffsll((unsigned long long)m) - 1;
            int sidx = chunk*64 + pos;
            if (cnt == 0) first = sidx;
            if (lane == 0) orow[cnt] = sidx;
            ++cnt;
            m &= m - 1;
        }
        if (cnt >= KK) break;
    }
    if (lane == 0)
        for (int j = cnt; j < KK; ++j) orow[j] = first;
}

// ---------- kernel 3: fused mkdp + FPS (k_geo) ----------
// Row r of dpf/ndp (flat 72-float rows of the (B,3,N,K) tensor). Lane k (<24)
// computes its point's 3 coords via the flat-scramble decode, writes dpf,
// then lane-parallel FPS writes permuted ndp.
__global__ __launch_bounds__(256) void k_geo(const float* __restrict__ p, const int* __restrict__ idx,
                                             float* __restrict__ dpf, float* __restrict__ ndp)
{
    int tid = threadIdx.x;
    int lane = tid & 31;                 // = k
    int row = blockIdx.x*8 + (tid >> 5); // grid 1024
    float px = 0.f, py = 0.f, pz = 0.f, dist;
    if (lane < KK) {
        float v[3];
        #pragma unroll
        for (int d = 0; d < 3; ++d) {
            int u = 3*lane + d;          // 0..71
            int qq = u / 24;             // 0..2
            int kk = u - qq*24;
            int m = row*3 + qq;          // block index in (B,3,N) blocks of 24
            int b = (m >= 3*NN) ? 1 : 0;
            int rem = m - b*3*NN;
            int dd = rem >> 12;          // /4096
            int n = rem & 4095;
            int base = (b << 12);
            int j = idx[((size_t)(base + n))*KK + kk];
            v[d] = p[(base + j)*3 + dd] - p[(base + n)*3 + dd];
        }
        px = v[0]; py = v[1]; pz = v[2];
        dist = 1e10f;
        float* drow = dpf + (size_t)row*72 + lane*3;
        drow[0] = px; drow[1] = py; drow[2] = pz;
    } else {
        dist = -3.4e38f;                 // idle lanes never win argmax
    }
    float* dst = ndp + (size_t)row*72;
    if (lane == 0) { dst[0] = px; dst[1] = py; dst[2] = pz; }
    int last = 0;
    for (int j = 1; j < KK; ++j) {
        float lx = __shfl(px, last, 32);
        float ly = __shfl(py, last, 32);
        float lz = __shfl(pz, last, 32);
        float dx = px-lx, dy = py-ly, dz = pz-lz;
        float d = dx*dx + dy*dy + dz*dz;
        dist = fminf(dist, d);
        float val = dist; int idxl = lane;
        #pragma unroll
        for (int off = 16; off > 0; off >>= 1) {
            float ov = __shfl_xor(val, off, 32);
            int   oi = __shfl_xor(idxl, off, 32);
            if (ov > val || (ov == val && oi < idxl)) { val = ov; idxl = oi; }
        }
        if (lane == idxl) { dst[j*3+0] = px; dst[j*3+1] = py; dst[j*3+2] = pz; }
        last = idxl;
    }
}

// ---------- kernel 5: displacement MLP (3->32->16->3) + residual -> q2 ----------
__global__ void k_mlp(const float* __restrict__ ndp,
                      const float* __restrict__ wd1, const float* __restrict__ gd1, const float* __restrict__ bd1,
                      const float* __restrict__ wd2, const float* __restrict__ gd2, const float* __restrict__ bd2,
                      const float* __restrict__ wd3, const float* __restrict__ gd3, const float* __restrict__ bd3,
                      float* __restrict__ q2)
{
    __shared__ float W1[96], S1[32], B1s[32], W2[512], S2[16], B2s[16], W3[48], S3[3], B3s[3];
    int tid = threadIdx.x;
    const float inv = sqrtf(1.00001f);
    for (int i = tid; i < 96;  i += blockDim.x) W1[i]=wd1[i];
    for (int i = tid; i < 512; i += blockDim.x) W2[i]=wd2[i];
    for (int i = tid; i < 48;  i += blockDim.x) W3[i]=wd3[i];
    if (tid < 32) { S1[tid]=gd1[tid]/inv; B1s[tid]=bd1[tid]; }
    if (tid >= 32 && tid < 48) { int c=tid-32; S2[c]=gd2[c]/inv; B2s[c]=bd2[c]; }
    if (tid >= 48 && tid < 51) { int c=tid-48; S3[c]=gd3[c]/inv; B3s[c]=bd3[c]; }
    __syncthreads();
    int t = blockIdx.x*blockDim.x + tid;   // 196608 exact
    int k = t % KK, n = (t/KK)%NN, b = t/(NN*KK);
    size_t base = (((size_t)b*3)*NN + n)*KK + k;
    float x0 = ndp[base], x1 = ndp[base + NKK], x2 = ndp[base + 2*(size_t)NKK];
    float h1[32];
    #pragma unroll
    for (int o = 0; o < 32; ++o)
        h1[o] = relu_((W1[o*3+0]*x0 + W1[o*3+1]*x1 + W1[o*3+2]*x2)*S1[o] + B1s[o]);
    float h2[16];
    #pragma unroll
    for (int o = 0; o < 16; ++o) {
        float a = 0.f;
        #pragma unroll
        for (int c = 0; c < 32; ++c) a += W2[o*32+c]*h1[c];
        h2[o] = relu_(a*S2[o] + B2s[o]);
    }
    float xv[3] = {x0, x1, x2};
    #pragma unroll
    for (int d = 0; d < 3; ++d) {
        float a = 0.f;
        #pragma unroll
        for (int c = 0; c < 16; ++c) a += W3[d*16+c]*h2[c];
        q2[base + (size_t)d*NKK] = xv[d] + (a*S3[d] + B3s[d]);
    }
}

// ---------- kernel 6: ball query 2 (k=1) + dp2 = s2[j2] - q2 ----------
__global__ void k_bq2(const float* __restrict__ dpf, const float* __restrict__ q2f,
                      int* __restrict__ idx2, float* __restrict__ dp2)
{
    int t = blockIdx.x*blockDim.x + threadIdx.x;   // 196608 exact
    int g = t / KK, kq = t % KK;
    const float* srow = dpf + (size_t)g*72;
    const float* qp   = q2f + (size_t)g*72 + kq*3;
    float qx=qp[0], qy=qp[1], qz=qp[2];
    float sq = qx*qx + qy*qy + qz*qz;
    const float rsq = (float)(0.15*0.15);
    int j2 = 0;
    for (int s = 0; s < KK; ++s) {
        float sx=srow[s*3+0], sy=srow[s*3+1], sz=srow[s*3+2];
        float ss  = sx*sx + sy*sy + sz*sz;
        float dot = qx*sx + qy*sy + qz*sz;
        float d2 = (sq + ss) - 2.0f*dot;
        if (d2 < rsq) { j2 = s; break; }
    }
    idx2[t] = j2;
    float* drow = dp2 + (size_t)g*72;
    drow[0*KK + kq] = srow[j2*3+0] - qx;
    drow[1*KK + kq] = srow[j2*3+1] - qy;
    drow[2*KK + kq] = srow[j2*3+2] - qz;
}

// ---------- kernel 7: fused gather + MFMA conv + softmax + pe + fout ----------
// R6: dual-n gather staging (GM[6400] = G0|G1, unions with M[48*132]), 4 barriers.
__global__ __launch_bounds__(256, 4) void k_final(
    const float* __restrict__ f1T, const int* __restrict__ idx, const int* __restrict__ idx2,
    const float* __restrict__ dp2, const unsigned short* __restrict__ wwAbf,
    const float* __restrict__ gw, const float* __restrict__ bw,
    const float* __restrict__ wc2, const float* __restrict__ gc2, const float* __restrict__ bc2,
    float* __restrict__ fout, float* __restrict__ pe)
{
    __shared__ float GM[6400];              // union: G[nl][c][kk] (2*128*25) | M[col][o] stride132 (6336)
    __shared__ unsigned short Fbf[48*128];  // bf16 [col][c], byte ^= (col&7)<<4
    __shared__ float Ds[2][3][KK];
    __shared__ int   IRs[2][KK];
    int tid = threadIdx.x;
    int bid = blockIdx.x;
    int b = bid >> 11;
    int n0 = (bid & 2047)*2;

    if (tid < 48) {
        int nl = tid/24, kk = tid%24;
        IRs[nl][kk] = idx[((size_t)b*NN + (n0+nl))*KK + kk];
    }
    if (tid >= 64 && tid < 208) {
        int u = tid-64; int nl = u/72, r = u%72, d = r/24, k = r%24;
        Ds[nl][d][k] = dp2[(((size_t)b*3 + d)*NN + (n0+nl))*KK + k];
    }
    int c = tid & 127, kh = tid >> 7;
    int i2r[12];
    {
        int g = (b*CO + c)*32 + (n0 >> 7);
        const int4* i4 = (const int4*)(idx2 + (size_t)g*KK) + kh*3;
        int4 a = i4[0], bq = i4[1], cq4 = i4[2];
        i2r[0]=a.x; i2r[1]=a.y; i2r[2]=a.z; i2r[3]=a.w;
        i2r[4]=bq.x; i2r[5]=bq.y; i2r[6]=bq.z; i2r[7]=bq.w;
        i2r[8]=cq4.x; i2r[9]=cq4.y; i2r[10]=cq4.z; i2r[11]=cq4.w;
    }
    int wv = tid >> 6, l = tid & 63;
    const short8* wwA8 = (const short8*)wwAbf;
    short8 Af[2][4];
    #pragma unroll
    for (int ot = 0; ot < 2; ++ot)
        #pragma unroll
        for (int ks = 0; ks < 4; ++ks)
            Af[ot][ks] = wwA8[((wv*2 + ot)*4 + ks)*64 + l];
    __syncthreads();                        // barrier 1 (IRs ready)

    // gather BOTH n tiles
    const float* basep = f1T + (size_t)b*NN*CO + c;
    #pragma unroll
    for (int nl = 0; nl < 2; ++nl)
        #pragma unroll
        for (int j = 0; j < 12; ++j) {
            int kk = kh*12 + j;
            GM[nl*3200 + c*25 + kk] = basep[(size_t)IRs[nl][kk]*CO];
        }
    __syncthreads();                        // barrier 2

    // permute both
    #pragma unroll
    for (int nl = 0; nl < 2; ++nl)
        #pragma unroll
        for (int j = 0; j < 12; ++j) {
            int col = nl*24 + kh*12 + j;
            unsigned int boff = (unsigned)((col*256 + c*2) ^ ((col&7)<<4));
            *(unsigned short*)((char*)Fbf + boff) = f2bf(GM[nl*3200 + c*25 + i2r[j]]);
        }
    __syncthreads();                        // barrier 3 (all G reads done -> GM reusable as M)

    {
        f32x4 acc[2][3];
        #pragma unroll
        for (int ot=0;ot<2;++ot)
            #pragma unroll
            for (int ct=0;ct<3;++ct)
                acc[ot][ct] = (f32x4){0.f,0.f,0.f,0.f};
        int row_l = l & 15, kc_l = (l >> 4) << 3;
        #pragma unroll
        for (int ct = 0; ct < 3; ++ct) {
            int row = ct*16 + row_l;
            #pragma unroll
            for (int ks = 0; ks < 4; ++ks) {
                unsigned int boff = (unsigned)((row*256 + (ks*32 + kc_l)*2) ^ ((row&7)<<4));
                short8 Bf = *(const short8*)((const char*)Fbf + boff);
                acc[0][ct] = __builtin_amdgcn_mfma_f32_16x16x32_bf16(Af[0][ks], Bf, acc[0][ct], 0,0,0);
                acc[1][ct] = __builtin_amdgcn_mfma_f32_16x16x32_bf16(Af[1][ks], Bf, acc[1][ct], 0,0,0);
            }
        }
        #pragma unroll
        for (int ot = 0; ot < 2; ++ot) {
            int o = wv*32 + ot*16 + ((l>>4)<<2);
            #pragma unroll
            for (int ct = 0; ct < 3; ++ct) {
                int col = ct*16 + (l & 15);
                *(f32x4*)&GM[col*132 + o] = acc[ot][ct];
            }
        }
    }
    __syncthreads();                        // barrier 4 (M ready)

    int op = (tid & 127) >> 1, half = tid & 1, nl = tid >> 7;
    int k0 = half*12;
    int o0 = op*2;
    int n  = n0 + nl;
    int colb = nl*24 + k0;
    float a0[12], a1[12];
    #pragma unroll
    for (int j = 0; j < 12; ++j) {
        float2 m2 = *(const float2*)&GM[(colb+j)*132 + o0];
        a0[j] = m2.x; a1[j] = m2.y;
    }
    const float inv = sqrtf(1.00001f);
    float sw0 = gw[o0]/inv,   bw0 = bw[o0];
    float sw1 = gw[o0+1]/inv, bw1 = bw[o0+1];
    float pev0[12], pev1[12];
    {
        float wa0=wc2[o0*3], wa1=wc2[o0*3+1], wa2=wc2[o0*3+2];
        float wb0=wc2[o0*3+3], wb1=wc2[o0*3+4], wb2=wc2[o0*3+5];
        float sca = gc2[o0]/inv,   bca = bc2[o0];
        float scb = gc2[o0+1]/inv, bcb = bc2[o0+1];
        #pragma unroll
        for (int j = 0; j < 12; ++j) {
            float d0 = Ds[nl][0][k0+j], d1 = Ds[nl][1][k0+j], d2 = Ds[nl][2][k0+j];
            pev0[j] = relu_((wa0*d0 + wa1*d1 + wa2*d2)*sca + bca);
            pev1[j] = relu_((wb0*d0 + wb1*d1 + wb2*d2)*scb + bcb);
        }
    }
    float m0 = -3.4e38f, m1 = -3.4e38f;
    #pragma unroll
    for (int j=0;j<12;++j){
        a0[j] = a0[j]*sw0 + bw0; m0 = fmaxf(m0, a0[j]);
        a1[j] = a1[j]*sw1 + bw1; m1 = fmaxf(m1, a1[j]);
    }
    m0 = fmaxf(m0, __shfl_xor(m0, 1));
    m1 = fmaxf(m1, __shfl_xor(m1, 1));
    float s0 = 0.f, s1 = 0.f;
    #pragma unroll
    for (int j=0;j<12;++j){
        a0[j] = __expf(a0[j]-m0); s0 += a0[j];
        a1[j] = __expf(a1[j]-m1); s1 += a1[j];
    }
    s0 += __shfl_xor(s0, 1);
    s1 += __shfl_xor(s1, 1);
    float rs0 = 1.0f/s0, rs1 = 1.0f/s1;
    float fo0 = -3.4e38f, fo1 = -3.4e38f;
    #pragma unroll
    for (int j=0;j<12;++j){
        unsigned int boff = (unsigned)(((colb+j)*256 + o0*2) ^ (((colb+j)&7)<<4));
        unsigned int v = *(const unsigned int*)((const char*)Fbf + boff);
        float fj0 = __uint_as_float((v & 0xffffu) << 16);
        float fj1 = __uint_as_float((v >> 16) << 16);
        fo0 = fmaxf(fo0, (pev0[j] + fj0)*a0[j]*rs0);
        fo1 = fmaxf(fo1, (pev1[j] + fj1)*a1[j]*rs1);
    }
    fo0 = fmaxf(fo0, __shfl_xor(fo0, 1));
    fo1 = fmaxf(fo1, __shfl_xor(fo1, 1));
    fout[((size_t)b*CO + o0+half)*NN + n] = half ? fo1 : fo0;
    float* pr0 = pe + (((size_t)b*CO + o0)*NN + n)*KK + k0;
    float* pr1 = pe + (((size_t)b*CO + o0+1)*NN + n)*KK + k0;
    #pragma unroll
    for (int q4 = 0; q4 < 3; ++q4) {
        float4 v0, v1;
        v0.x=pev0[q4*4+0]; v0.y=pev0[q4*4+1]; v0.z=pev0[q4*4+2]; v0.w=pev0[q4*4+3];
        v1.x=pev1[q4*4+0]; v1.y=pev1[q4*4+1]; v1.z=pev1[q4*4+2]; v1.w=pev1[q4*4+3];
        ((float4*)pr0)[q4] = v0;
        ((float4*)pr1)[q4] = v1;
    }
}

extern "C" void kernel_launch(void* const* d_in, const int* in_sizes, int n_in,
                              void* d_out, int out_size, void* d_ws, size_t ws_size,
                              hipStream_t stream)
{
    const float* pc  = (const float*)d_in[0];
    const float* f   = (const float*)d_in[1];
    const float* w1  = (const float*)d_in[3];
    const float* g1  = (const float*)d_in[4];
    const float* b1  = (const float*)d_in[5];
    const float* wd1 = (const float*)d_in[6];
    const float* gd1 = (const float*)d_in[7];
    const float* bd1 = (const float*)d_in[8];
    const float* wd2 = (const float*)d_in[9];
    const float* gd2 = (const float*)d_in[10];
    const float* bd2 = (const float*)d_in[11];
    const float* wd3 = (const float*)d_in[12];
    const float* gd3 = (const float*)d_in[13];
    const float* bd3 = (const float*)d_in[14];
    const float* ww  = (const float*)d_in[15];
    const float* gw  = (const float*)d_in[16];
    const float* bw  = (const float*)d_in[17];
    const float* wc2 = (const float*)d_in[18];
    const float* gc2 = (const float*)d_in[19];
    const float* bc2 = (const float*)d_in[20];

    float* out     = (float*)d_out;
    float* outPc   = out;                               // 49152
    float* outFout = out + 49152;                       // 1048576
    float* outPe   = out + 49152 + 1048576;             // 25165824

    char* ws = (char*)d_ws;
    size_t off = 0;
    auto alloc = [&](size_t bytes)->void* {
        void* q = ws + off; off += (bytes + 255) & ~(size_t)255; return q;
    };
    float* p    = (float*)alloc((size_t)GQ*3*4);
    float* pS   = (float*)alloc((size_t)GQ*3*4);
    float* f1T  = (float*)alloc((size_t)BB*NN*CO*4);
    int*   idx  = (int*)  alloc((size_t)BB*NN*KK*4);
    float* dpf  = (float*)alloc((size_t)BB*3*NN*KK*4);
    float* ndp  = (float*)alloc((size_t)BB*3*NN*KK*4);
    float* q2f  = (float*)alloc((size_t)BB*3*NN*KK*4);
    int*   idx2 = (int*)  alloc((size_t)GQ*KK*4);
    float* dp2  = (float*)alloc((size_t)GQ*72*4);
    unsigned short* wwAbf = (unsigned short*)alloc((size_t)CO*CO*2);

    k_f1   <<<dim3(512), dim3(256), 0, stream>>>(f, w1, g1, b1, pc, ww, f1T, outPc, p, pS, wwAbf);
    k_bq1  <<<dim3(GQ/4), dim3(256), 0, stream>>>(pS, idx);
    k_geo  <<<dim3(GQ/8), dim3(256), 0, stream>>>(p, idx, dpf, ndp);
    k_mlp  <<<dim3((BB*NN*KK)/256), dim3(256), 0, stream>>>(ndp, wd1,gd1,bd1, wd2,gd2,bd2, wd3,gd3,bd3, q2f);
    k_bq2  <<<dim3((GQ*KK)/256), dim3(256), 0, stream>>>(dpf, q2f, idx2, dp2);
    k_final<<<dim3(BB*NN/2), dim3(256), 0, stream>>>(f1T, idx, idx2, dp2, wwAbf, gw, bw, wc2, gc2, bc2, outFout, outPe);
}